// Round 3
// baseline (544.875 us; speedup 1.0000x reference)
//
#include <hip/hip_runtime.h>
#include <math.h>

#define N_NODES 100000
#define N_EDGES 1600000
#define F_IN    500
#define HIDDEN  64
#define N_CLASS 40
#define KPAD    512

#define NB   2048      // dst buckets
#define NPB  49        // nodes per bucket (2048*49 = 100352 >= N)
#define EPB  16384     // edges per block in bhist/bfill
#define CAP  1536      // LDS pair capacity in k_bucket_csr

typedef __attribute__((ext_vector_type(4))) float f32x4;
typedef __attribute__((ext_vector_type(8))) __bf16 bf16x8;

__device__ __forceinline__ unsigned short f2bf(float f) {
    unsigned int u = __float_as_uint(f);
    u = (u + 0x7FFF + ((u >> 16) & 1)) >> 16;   // RNE
    return (unsigned short)u;
}
__device__ __forceinline__ unsigned int packbf(float a, float b) {
    return (unsigned int)f2bf(a) | ((unsigned int)f2bf(b) << 16);
}
__device__ __forceinline__ float bfu_lo(unsigned int v) {   // low ushort -> float
    return __uint_as_float(v << 16);
}
__device__ __forceinline__ float bfu_hi(unsigned int v) {   // high ushort -> float
    return __uint_as_float(v & 0xFFFF0000u);
}

// W1t[n][k] = bf16(W1[k][n]), k zero-padded to 512; also zeroes bcnt (merged launch)
__global__ void k_prep_w1t(const float* __restrict__ w1, unsigned short* __restrict__ w1t,
                           int* __restrict__ bcnt) {
    int idx = blockIdx.x * blockDim.x + threadIdx.x;
    if (idx < NB) bcnt[idx] = 0;
    if (idx >= HIDDEN * KPAD) return;
    int n = idx >> 9, k = idx & (KPAD - 1);
    float v = (k < F_IN) ? w1[k * HIDDEN + n] : 0.f;
    w1t[idx] = f2bf(v);
}

// ---------- CSR build: bucketed counting sort ----------
__launch_bounds__(1024)
__global__ void k_bhist(const int* __restrict__ dst, int* __restrict__ bcnt, int e) {
    __shared__ int h[NB];
    for (int i = threadIdx.x; i < NB; i += 1024) h[i] = 0;
    __syncthreads();
    int base = blockIdx.x * EPB;
#pragma unroll
    for (int j = 0; j < 16; ++j) {
        int i = base + j * 1024 + threadIdx.x;
        if (i < e) atomicAdd(&h[dst[i] / NPB], 1);
    }
    __syncthreads();
    for (int i = threadIdx.x; i < NB; i += 1024)
        if (h[i]) atomicAdd(&bcnt[i], h[i]);
}

__launch_bounds__(1024)
__global__ void k_bscan(const int* __restrict__ bcnt, int* __restrict__ bptr,
                        int* __restrict__ bcur) {
    __shared__ int s[1024];
    int t = threadIdx.x;
    int a = bcnt[2 * t], b = bcnt[2 * t + 1];
    int v = a + b;
    s[t] = v;
    __syncthreads();
    for (int off = 1; off < 1024; off <<= 1) {
        int u = (t >= off) ? s[t - off] : 0;
        __syncthreads();
        s[t] += u;
        __syncthreads();
    }
    int excl = s[t] - v;
    bptr[2 * t] = excl;     bptr[2 * t + 1] = excl + a;
    bcur[2 * t] = excl;     bcur[2 * t + 1] = excl + a;
    if (t == 1023) bptr[NB] = s[1023];
}

__launch_bounds__(1024)
__global__ void k_bfill(const int* __restrict__ src, const int* __restrict__ dst,
                        int* __restrict__ bcur, int2* __restrict__ ebuf, int e) {
    __shared__ int hist[NB];
    __shared__ int base_[NB];
    for (int i = threadIdx.x; i < NB; i += 1024) hist[i] = 0;
    __syncthreads();
    int b0 = blockIdx.x * EPB;
    int s_[16], d_[16];
#pragma unroll
    for (int j = 0; j < 16; ++j) {
        int i = b0 + j * 1024 + threadIdx.x;
        if (i < e) {
            s_[j] = src[i];
            d_[j] = dst[i];
            atomicAdd(&hist[d_[j] / NPB], 1);
        } else d_[j] = -1;
    }
    __syncthreads();
    for (int i = threadIdx.x; i < NB; i += 1024) {
        int hc = hist[i];
        base_[i] = hc ? atomicAdd(&bcur[i], hc) : 0;
        hist[i] = 0;    // reuse as local cursor
    }
    __syncthreads();
#pragma unroll
    for (int j = 0; j < 16; ++j) {
        if (d_[j] >= 0) {
            int bu = d_[j] / NPB;
            int r = atomicAdd(&hist[bu], 1);
            ebuf[base_[bu] + r] = make_int2(s_[j], d_[j]);
        }
    }
}

__launch_bounds__(256)
__global__ void k_bucket_csr(const int2* __restrict__ ebuf, const int* __restrict__ bptr,
                             int* __restrict__ rp, int* __restrict__ col,
                             float* __restrict__ dinv, int n) {
    int b  = blockIdx.x;
    int lo = b * NPB;
    if (lo >= n) return;
    int hi  = min(lo + NPB, n);
    int eb0 = bptr[b], ec = bptr[b + 1] - eb0;

    __shared__ int2 pairs[CAP];
    __shared__ int  hist[NPB];
    __shared__ int  excl[NPB + 1];
    for (int j = threadIdx.x; j < NPB; j += 256) hist[j] = 0;
    __syncthreads();
    for (int i = threadIdx.x; i < ec; i += 256) {
        int2 p = ebuf[eb0 + i];
        if (i < CAP) pairs[i] = p;
        atomicAdd(&hist[p.y - lo], 1);
    }
    __syncthreads();
    if (threadIdx.x == 0) {
        int acc = 0;
        for (int j = 0; j < NPB; ++j) { excl[j] = acc; acc += hist[j]; }
        excl[NPB] = acc;
    }
    __syncthreads();
    for (int j = threadIdx.x; j < hi - lo; j += 256) {
        rp[lo + j]   = eb0 + excl[j];
        dinv[lo + j] = rsqrtf((float)(hist[j] + 1));   // +1 self loop
    }
    if (hi == n && threadIdx.x == 0) rp[n] = eb0 + ec;
    __syncthreads();
    for (int j = threadIdx.x; j < NPB; j += 256) hist[j] = 0;  // reuse as cursor
    __syncthreads();
    for (int i = threadIdx.x; i < ec; i += 256) {
        int2 p  = (i < CAP) ? pairs[i] : ebuf[eb0 + i];
        int  li = p.y - lo;
        int  r  = atomicAdd(&hist[li], 1);
        col[eb0 + excl[li] + r] = p.x;
    }
}

// ---------- GEMM1: hs[N,64](bf16, pre-scaled by dinv) = dinv * (x @ W1) ----------
// Direct-to-register A fragments: lane (quad,l16) reads 32 contiguous bytes of
// x row (rowb + rt*16 + l16) at column ks*32 + quad*8 -> exactly the MFMA
// 16x16x32 A layout. No LDS, no barriers; each x element read exactly once;
// 16 independent K-iterations give the compiler free pipelining room.
__launch_bounds__(256)
__global__ void k_gemm1(const float* __restrict__ x, const unsigned short* __restrict__ w1t,
                        const float* __restrict__ dinv, unsigned short* __restrict__ hs, int n) {
    const int tid  = threadIdx.x;
    const int wave = tid >> 6;
    const int lane = tid & 63;
    const int quad = lane >> 4;
    const int l16  = lane & 15;
    const int rowb = blockIdx.x * 128 + wave * 32;

    const int r0 = rowb + l16;          // rt = 0 fragment row
    const int r1 = rowb + 16 + l16;     // rt = 1 fragment row
    const bool v0 = r0 < n, v1 = r1 < n;
    const float* p0 = &x[(size_t)(v0 ? r0 : 0) * F_IN];
    const float* p1 = &x[(size_t)(v1 ? r1 : 0) * F_IN];
    const float4 z4 = make_float4(0.f, 0.f, 0.f, 0.f);

    f32x4 acc[2][4];
#pragma unroll
    for (int rt = 0; rt < 2; ++rt)
#pragma unroll
        for (int ct = 0; ct < 4; ++ct) acc[rt][ct] = (f32x4)0.f;

#pragma unroll 3
    for (int ks = 0; ks < 15; ++ks) {
        const int c0 = ks * 32 + quad * 8;
        float4 a00 = v0 ? *(const float4*)&p0[c0]     : z4;
        float4 a01 = v0 ? *(const float4*)&p0[c0 + 4] : z4;
        float4 a10 = v1 ? *(const float4*)&p1[c0]     : z4;
        float4 a11 = v1 ? *(const float4*)&p1[c0 + 4] : z4;

        bf16x8 bfrag[4];
#pragma unroll
        for (int ct = 0; ct < 4; ++ct)
            bfrag[ct] = *(const bf16x8*)&w1t[(ct * 16 + l16) * KPAD + ks * 32 + quad * 8];

        union { bf16x8 v; unsigned int u[4]; } af[2];
        af[0].u[0] = packbf(a00.x, a00.y); af[0].u[1] = packbf(a00.z, a00.w);
        af[0].u[2] = packbf(a01.x, a01.y); af[0].u[3] = packbf(a01.z, a01.w);
        af[1].u[0] = packbf(a10.x, a10.y); af[1].u[1] = packbf(a10.z, a10.w);
        af[1].u[2] = packbf(a11.x, a11.y); af[1].u[3] = packbf(a11.z, a11.w);

#pragma unroll
        for (int rt = 0; rt < 2; ++rt)
#pragma unroll
            for (int ct = 0; ct < 4; ++ct)
                acc[rt][ct] = __builtin_amdgcn_mfma_f32_16x16x32_bf16(
                    rt ? af[1].v : af[0].v, bfrag[ct], acc[rt][ct], 0, 0, 0);
    }
    {   // peeled ks = 15: columns 480..511; only chunks fully below F_IN load
        const int c0 = 480 + quad * 8;
        const bool cv0 = (c0 + 4 <= F_IN);      // false only for quad 3
        const bool cv1 = (c0 + 8 <= F_IN);      // false for quads 2,3
        float4 a00 = (v0 && cv0) ? *(const float4*)&p0[c0]     : z4;
        float4 a01 = (v0 && cv1) ? *(const float4*)&p0[c0 + 4] : z4;
        float4 a10 = (v1 && cv0) ? *(const float4*)&p1[c0]     : z4;
        float4 a11 = (v1 && cv1) ? *(const float4*)&p1[c0 + 4] : z4;

        bf16x8 bfrag[4];
#pragma unroll
        for (int ct = 0; ct < 4; ++ct)
            bfrag[ct] = *(const bf16x8*)&w1t[(ct * 16 + l16) * KPAD + 480 + quad * 8];

        union { bf16x8 v; unsigned int u[4]; } af[2];
        af[0].u[0] = packbf(a00.x, a00.y); af[0].u[1] = packbf(a00.z, a00.w);
        af[0].u[2] = packbf(a01.x, a01.y); af[0].u[3] = packbf(a01.z, a01.w);
        af[1].u[0] = packbf(a10.x, a10.y); af[1].u[1] = packbf(a10.z, a10.w);
        af[1].u[2] = packbf(a11.x, a11.y); af[1].u[3] = packbf(a11.z, a11.w);

#pragma unroll
        for (int rt = 0; rt < 2; ++rt)
#pragma unroll
            for (int ct = 0; ct < 4; ++ct)
                acc[rt][ct] = __builtin_amdgcn_mfma_f32_16x16x32_bf16(
                    rt ? af[1].v : af[0].v, bfrag[ct], acc[rt][ct], 0, 0, 0);
    }

    // D layout: row = quad*4 + reg, col = lane&15 ; store bf16 * dinv[row]
#pragma unroll
    for (int rt = 0; rt < 2; ++rt) {
#pragma unroll
        for (int reg = 0; reg < 4; ++reg) {
            int grow = rowb + rt * 16 + quad * 4 + reg;
            if (grow < n) {
                float dv = dinv[grow];
#pragma unroll
                for (int ct = 0; ct < 4; ++ct)
                    hs[(size_t)grow * HIDDEN + ct * 16 + l16] = f2bf(dv * acc[rt][ct][reg]);
            }
        }
    }
}

// ---------- aggregation over pre-scaled bf16 table ----------
// out[i] = dinv[i] * (sum_e hs[col[e]] + hs[i]) + b  (+ReLU or +log_softmax)
// 4 edge streams per wave (16-lane quarters), uint2 (4 bf16 feats) per lane.
// Main loop keeps 16 gathers in flight; fixed 2-step epilogue bounds the
// dependent-chain depth for the remainder (<=3 edges per stream).
template <int F, bool RELU, bool LSM>
__launch_bounds__(256)
__global__ void k_agg(const uint2* __restrict__ hs2, const int* __restrict__ rp,
                      const int* __restrict__ col, const float* __restrict__ dinv,
                      const float* __restrict__ bias, float* __restrict__ out, int n) {
    constexpr int PW2 = F / 4;     // uint2 per row (16 or 10)
    const int lane = threadIdx.x & 63;
    const int q    = lane >> 4;    // edge-stream id 0..3
    const int p    = lane & 15;    // feature-slot within stream
    const bool act = p < PW2;
    int wid = __builtin_amdgcn_readfirstlane((blockIdx.x * blockDim.x + threadIdx.x) >> 6);
    const int nw = (gridDim.x * blockDim.x) >> 6;

    for (; wid < n; wid += nw) {
        const int beg = rp[wid], end = rp[wid + 1];
        float a0 = 0.f, a1 = 0.f, a2 = 0.f, a3 = 0.f;
        int e = beg + q;
        for (; e + 12 < end; e += 16) {          // 16 edges/wave-iter, 16 gathers in flight
            int c0 = col[e], c1 = col[e + 4], c2 = col[e + 8], c3 = col[e + 12];
            uint2 v0 = act ? hs2[(unsigned)c0 * PW2 + p] : make_uint2(0u, 0u);
            uint2 v1 = act ? hs2[(unsigned)c1 * PW2 + p] : make_uint2(0u, 0u);
            uint2 v2 = act ? hs2[(unsigned)c2 * PW2 + p] : make_uint2(0u, 0u);
            uint2 v3 = act ? hs2[(unsigned)c3 * PW2 + p] : make_uint2(0u, 0u);
            a0 += bfu_lo(v0.x) + bfu_lo(v1.x) + bfu_lo(v2.x) + bfu_lo(v3.x);
            a1 += bfu_hi(v0.x) + bfu_hi(v1.x) + bfu_hi(v2.x) + bfu_hi(v3.x);
            a2 += bfu_lo(v0.y) + bfu_lo(v1.y) + bfu_lo(v2.y) + bfu_lo(v3.y);
            a3 += bfu_hi(v0.y) + bfu_hi(v1.y) + bfu_hi(v2.y) + bfu_hi(v3.y);
        }
        if (e + 4 < end) {                       // >=2 edges left in this stream
            int c0 = col[e], c1 = col[e + 4];
            uint2 v0 = act ? hs2[(unsigned)c0 * PW2 + p] : make_uint2(0u, 0u);
            uint2 v1 = act ? hs2[(unsigned)c1 * PW2 + p] : make_uint2(0u, 0u);
            a0 += bfu_lo(v0.x) + bfu_lo(v1.x);
            a1 += bfu_hi(v0.x) + bfu_hi(v1.x);
            a2 += bfu_lo(v0.y) + bfu_lo(v1.y);
            a3 += bfu_hi(v0.y) + bfu_hi(v1.y);
            e += 8;
        }
        if (e < end) {                           // last remaining edge
            int c0 = col[e];
            uint2 v0 = act ? hs2[(unsigned)c0 * PW2 + p] : make_uint2(0u, 0u);
            a0 += bfu_lo(v0.x); a1 += bfu_hi(v0.x);
            a2 += bfu_lo(v0.y); a3 += bfu_hi(v0.y);
        }
        // combine the 4 stream partials
        a0 += __shfl_xor(a0, 16); a1 += __shfl_xor(a1, 16);
        a2 += __shfl_xor(a2, 16); a3 += __shfl_xor(a3, 16);
        a0 += __shfl_xor(a0, 32); a1 += __shfl_xor(a1, 32);
        a2 += __shfl_xor(a2, 32); a3 += __shfl_xor(a3, 32);

        const float di = dinv[wid];
        uint2 sv  = act ? hs2[(unsigned)wid * PW2 + p] : make_uint2(0u, 0u);
        float4 bv = act ? *(const float4*)&bias[4 * p] : make_float4(0.f, 0.f, 0.f, 0.f);
        float r0 = di * (a0 + bfu_lo(sv.x)) + bv.x;
        float r1 = di * (a1 + bfu_hi(sv.x)) + bv.y;
        float r2 = di * (a2 + bfu_lo(sv.y)) + bv.z;
        float r3 = di * (a3 + bfu_hi(sv.y)) + bv.w;
        if (RELU) {
            r0 = fmaxf(r0, 0.f); r1 = fmaxf(r1, 0.f);
            r2 = fmaxf(r2, 0.f); r3 = fmaxf(r3, 0.f);
        }
        if (LSM) {
            float m = act ? fmaxf(fmaxf(r0, r1), fmaxf(r2, r3)) : -INFINITY;
#pragma unroll
            for (int off = 8; off; off >>= 1) m = fmaxf(m, __shfl_xor(m, off));
            float ex = act ? (__expf(r0 - m) + __expf(r1 - m) + __expf(r2 - m) + __expf(r3 - m))
                           : 0.f;
#pragma unroll
            for (int off = 8; off; off >>= 1) ex += __shfl_xor(ex, off);
            float lse = m + __logf(ex);
            r0 -= lse; r1 -= lse; r2 -= lse; r3 -= lse;
        }
        if (q == 0 && act)
            *(float4*)&out[(size_t)wid * F + 4 * p] = make_float4(r0, r1, r2, r3);
    }
}

// ---------- GEMM2: h2s[N,40](bf16, pre-scaled) = dinv * (a[N,64] @ W2[64,40]) ----------
__launch_bounds__(256)
__global__ void k_gemm2(const float* __restrict__ a, const float* __restrict__ w,
                        const float* __restrict__ dinv, unsigned short* __restrict__ out, int n) {
    __shared__ float ws[HIDDEN * N_CLASS];
    for (int idx = threadIdx.x; idx < HIDDEN * N_CLASS; idx += 256) ws[idx] = w[idx];
    __syncthreads();
    int idx = blockIdx.x * 256 + threadIdx.x;
    if (idx >= n * N_CLASS) return;
    int i = idx / N_CLASS, j = idx - i * N_CLASS;
    float s = 0.f;
#pragma unroll
    for (int k = 0; k < HIDDEN; k += 4) {
        float4 xv = *(const float4*)&a[(size_t)i * HIDDEN + k];
        s = fmaf(xv.x, ws[k * N_CLASS + j], s);
        s = fmaf(xv.y, ws[(k + 1) * N_CLASS + j], s);
        s = fmaf(xv.z, ws[(k + 2) * N_CLASS + j], s);
        s = fmaf(xv.w, ws[(k + 3) * N_CLASS + j], s);
    }
    out[idx] = f2bf(dinv[i] * s);
}

extern "C" void kernel_launch(void* const* d_in, const int* in_sizes, int n_in,
                              void* d_out, int out_size, void* d_ws, size_t ws_size,
                              hipStream_t stream) {
    const float* x   = (const float*)d_in[0];
    const float* W1  = (const float*)d_in[1];
    const float* b1  = (const float*)d_in[2];
    const float* W2  = (const float*)d_in[3];
    const float* b2  = (const float*)d_in[4];
    const int*   ei  = (const int*)d_in[5];
    const int*   src = ei;
    const int*   dst = ei + N_EDGES;
    float*       out = (float*)d_out;

    char*  ws  = (char*)d_ws;
    size_t off = 0;
    auto alloc = [&](size_t bytes) -> void* {
        void* p = ws + off;
        off += (bytes + 255) & ~(size_t)255;
        return p;
    };
    int*            bcnt = (int*)alloc((size_t)NB * 4);
    int*            bptr = (int*)alloc((size_t)(NB + 1) * 4);
    int*            bcur = (int*)alloc((size_t)NB * 4);
    int*            rp   = (int*)alloc((size_t)(N_NODES + 1) * 4);
    int*            col  = (int*)alloc((size_t)N_EDGES * 4);
    float*          dinv = (float*)alloc((size_t)N_NODES * 4);
    unsigned short* w1t  = (unsigned short*)alloc((size_t)HIDDEN * KPAD * 2);
    unsigned short* h1s  = (unsigned short*)alloc((size_t)N_NODES * HIDDEN * 2);  // bf16, pre-scaled
    float*          h1a  = (float*)alloc((size_t)N_NODES * HIDDEN * 4);           // fp32
    int2*           ebuf = (int2*)h1a;            // alias: ebuf dead before agg1 writes h1a
    unsigned short* h2s  = h1s;                   // bf16, aliases h1s (dead after agg1)

    const int NBH = (N_EDGES + EPB - 1) / EPB;   // 98

    // CSR build (bucketed counting sort) + W1^T prep (also zeroes bcnt)
    k_prep_w1t<<<(HIDDEN * KPAD + 255) / 256, 256, 0, stream>>>(W1, w1t, bcnt);
    k_bhist<<<NBH, 1024, 0, stream>>>(dst, bcnt, N_EDGES);
    k_bscan<<<1, 1024, 0, stream>>>(bcnt, bptr, bcur);
    k_bfill<<<NBH, 1024, 0, stream>>>(src, dst, bcur, ebuf, N_EDGES);
    k_bucket_csr<<<NB, 256, 0, stream>>>(ebuf, bptr, rp, col, dinv, N_NODES);

    // layer 1
    k_gemm1<<<(N_NODES + 127) / 128, 256, 0, stream>>>(x, w1t, dinv, h1s, N_NODES);
    k_agg<HIDDEN, true, false><<<2048, 256, 0, stream>>>(
        (const uint2*)h1s, rp, col, dinv, b1, h1a, N_NODES);

    // layer 2 (+fused log_softmax)
    k_gemm2<<<(N_NODES * N_CLASS + 255) / 256, 256, 0, stream>>>(h1a, W2, dinv, h2s, N_NODES);
    k_agg<N_CLASS, false, true><<<2048, 256, 0, stream>>>(
        (const uint2*)h2s, rp, col, dinv, b2, out, N_NODES);
}

// Round 4
// 526.404 us; speedup vs baseline: 1.0351x; 1.0351x over previous
//
#include <hip/hip_runtime.h>
#include <math.h>

#define N_NODES 100000
#define N_EDGES 1600000
#define F_IN    500
#define HIDDEN  64
#define N_CLASS 40
#define KPAD    512

#define NB   2048      // dst buckets
#define NPB  49        // nodes per bucket (2048*49 = 100352 >= N)
#define EPB  16384     // edges per block in bhist/bfill
#define CAP  1536      // LDS pair capacity in k_bucket_csr

typedef __attribute__((ext_vector_type(4))) float f32x4;
typedef __attribute__((ext_vector_type(8))) __bf16 bf16x8;

__device__ __forceinline__ unsigned short f2bf(float f) {
    unsigned int u = __float_as_uint(f);
    u = (u + 0x7FFF + ((u >> 16) & 1)) >> 16;   // RNE
    return (unsigned short)u;
}
__device__ __forceinline__ unsigned int packbf(float a, float b) {
    return (unsigned int)f2bf(a) | ((unsigned int)f2bf(b) << 16);
}
__device__ __forceinline__ float bfu_lo(unsigned int v) {   // low ushort -> float
    return __uint_as_float(v << 16);
}
__device__ __forceinline__ float bfu_hi(unsigned int v) {   // high ushort -> float
    return __uint_as_float(v & 0xFFFF0000u);
}

// W1t[n][k] = bf16(W1[k][n]), k zero-padded to 512; also zeroes bcnt (merged launch)
__global__ void k_prep_w1t(const float* __restrict__ w1, unsigned short* __restrict__ w1t,
                           int* __restrict__ bcnt) {
    int idx = blockIdx.x * blockDim.x + threadIdx.x;
    if (idx < NB) bcnt[idx] = 0;
    if (idx >= HIDDEN * KPAD) return;
    int n = idx >> 9, k = idx & (KPAD - 1);
    float v = (k < F_IN) ? w1[k * HIDDEN + n] : 0.f;
    w1t[idx] = f2bf(v);
}

// ---------- CSR build: bucketed counting sort ----------
__launch_bounds__(1024)
__global__ void k_bhist(const int* __restrict__ dst, int* __restrict__ bcnt, int e) {
    __shared__ int h[NB];
    for (int i = threadIdx.x; i < NB; i += 1024) h[i] = 0;
    __syncthreads();
    int base = blockIdx.x * EPB;
#pragma unroll
    for (int j = 0; j < 16; ++j) {
        int i = base + j * 1024 + threadIdx.x;
        if (i < e) atomicAdd(&h[dst[i] / NPB], 1);
    }
    __syncthreads();
    for (int i = threadIdx.x; i < NB; i += 1024)
        if (h[i]) atomicAdd(&bcnt[i], h[i]);
}

__launch_bounds__(1024)
__global__ void k_bscan(const int* __restrict__ bcnt, int* __restrict__ bptr,
                        int* __restrict__ bcur) {
    __shared__ int s[1024];
    int t = threadIdx.x;
    int a = bcnt[2 * t], b = bcnt[2 * t + 1];
    int v = a + b;
    s[t] = v;
    __syncthreads();
    for (int off = 1; off < 1024; off <<= 1) {
        int u = (t >= off) ? s[t - off] : 0;
        __syncthreads();
        s[t] += u;
        __syncthreads();
    }
    int excl = s[t] - v;
    bptr[2 * t] = excl;     bptr[2 * t + 1] = excl + a;
    bcur[2 * t] = excl;     bcur[2 * t + 1] = excl + a;
    if (t == 1023) bptr[NB] = s[1023];
}

__launch_bounds__(1024)
__global__ void k_bfill(const int* __restrict__ src, const int* __restrict__ dst,
                        int* __restrict__ bcur, int2* __restrict__ ebuf, int e) {
    __shared__ int hist[NB];
    __shared__ int base_[NB];
    for (int i = threadIdx.x; i < NB; i += 1024) hist[i] = 0;
    __syncthreads();
    int b0 = blockIdx.x * EPB;
    int s_[16], d_[16];
#pragma unroll
    for (int j = 0; j < 16; ++j) {
        int i = b0 + j * 1024 + threadIdx.x;
        if (i < e) {
            s_[j] = src[i];
            d_[j] = dst[i];
            atomicAdd(&hist[d_[j] / NPB], 1);
        } else d_[j] = -1;
    }
    __syncthreads();
    for (int i = threadIdx.x; i < NB; i += 1024) {
        int hc = hist[i];
        base_[i] = hc ? atomicAdd(&bcur[i], hc) : 0;
        hist[i] = 0;    // reuse as local cursor
    }
    __syncthreads();
#pragma unroll
    for (int j = 0; j < 16; ++j) {
        if (d_[j] >= 0) {
            int bu = d_[j] / NPB;
            int r = atomicAdd(&hist[bu], 1);
            ebuf[base_[bu] + r] = make_int2(s_[j], d_[j]);
        }
    }
}

__launch_bounds__(256)
__global__ void k_bucket_csr(const int2* __restrict__ ebuf, const int* __restrict__ bptr,
                             int* __restrict__ rp, int* __restrict__ col,
                             float* __restrict__ dinv, int n) {
    int b  = blockIdx.x;
    int lo = b * NPB;
    if (lo >= n) return;
    int hi  = min(lo + NPB, n);
    int eb0 = bptr[b], ec = bptr[b + 1] - eb0;

    __shared__ int2 pairs[CAP];
    __shared__ int  hist[NPB];
    __shared__ int  excl[NPB + 1];
    for (int j = threadIdx.x; j < NPB; j += 256) hist[j] = 0;
    __syncthreads();
    for (int i = threadIdx.x; i < ec; i += 256) {
        int2 p = ebuf[eb0 + i];
        if (i < CAP) pairs[i] = p;
        atomicAdd(&hist[p.y - lo], 1);
    }
    __syncthreads();
    if (threadIdx.x == 0) {
        int acc = 0;
        for (int j = 0; j < NPB; ++j) { excl[j] = acc; acc += hist[j]; }
        excl[NPB] = acc;
    }
    __syncthreads();
    for (int j = threadIdx.x; j < hi - lo; j += 256) {
        rp[lo + j]   = eb0 + excl[j];
        dinv[lo + j] = rsqrtf((float)(hist[j] + 1));   // +1 self loop
    }
    if (hi == n && threadIdx.x == 0) rp[n] = eb0 + ec;
    __syncthreads();
    for (int j = threadIdx.x; j < NPB; j += 256) hist[j] = 0;  // reuse as cursor
    __syncthreads();
    for (int i = threadIdx.x; i < ec; i += 256) {
        int2 p  = (i < CAP) ? pairs[i] : ebuf[eb0 + i];
        int  li = p.y - lo;
        int  r  = atomicAdd(&hist[li], 1);
        col[eb0 + excl[li] + r] = p.x;
    }
}

// ---------- GEMM1: hs[N,64](bf16, pre-scaled by dinv) = dinv * (x @ W1) ----------
// v3: one 16-row fragment per wave (grid 2x -> ~24 waves/CU) + explicit 1-deep
// register prefetch of the next K-slice so the vmcnt wait for ks+1 sits behind
// the bfrag loads + 4 MFMAs of ks. No LDS, no barriers; x read exactly once.
__launch_bounds__(256)
__global__ void k_gemm1(const float* __restrict__ x, const unsigned short* __restrict__ w1t,
                        const float* __restrict__ dinv, unsigned short* __restrict__ hs, int n) {
    const int tid  = threadIdx.x;
    const int wave = tid >> 6;
    const int lane = tid & 63;
    const int quad = lane >> 4;
    const int l16  = lane & 15;
    const int rowb = blockIdx.x * 64 + wave * 16;

    const int  row = rowb + l16;
    const bool vr  = row < n;
    const float* p = &x[(size_t)(vr ? row : 0) * F_IN];
    const float4 z4 = make_float4(0.f, 0.f, 0.f, 0.f);

    f32x4 acc[4];
#pragma unroll
    for (int ct = 0; ct < 4; ++ct) acc[ct] = (f32x4)0.f;

    auto COMPUTE = [&](int ks, const float4& ca, const float4& cb) {
        bf16x8 bfrag[4];
#pragma unroll
        for (int ct = 0; ct < 4; ++ct)
            bfrag[ct] = *(const bf16x8*)&w1t[(ct * 16 + l16) * KPAD + ks * 32 + quad * 8];
        union { bf16x8 v; unsigned int u[4]; } af;
        af.u[0] = packbf(ca.x, ca.y); af.u[1] = packbf(ca.z, ca.w);
        af.u[2] = packbf(cb.x, cb.y); af.u[3] = packbf(cb.z, cb.w);
#pragma unroll
        for (int ct = 0; ct < 4; ++ct)
            acc[ct] = __builtin_amdgcn_mfma_f32_16x16x32_bf16(af.v, bfrag[ct], acc[ct], 0, 0, 0);
    };

    float4 ca, cb, na, nb;
    {   // ks = 0
        const int c0 = quad * 8;
        ca = vr ? *(const float4*)&p[c0]     : z4;
        cb = vr ? *(const float4*)&p[c0 + 4] : z4;
    }
    for (int ks = 0; ks < 14; ++ks) {            // prefetch ks+1 (<= 14: full columns)
        const int c1 = (ks + 1) * 32 + quad * 8;
        na = vr ? *(const float4*)&p[c1]     : z4;
        nb = vr ? *(const float4*)&p[c1 + 4] : z4;
        COMPUTE(ks, ca, cb);
        ca = na; cb = nb;
    }
    {   // iteration 14: prefetch ks=15 with column predicates (F_IN = 500)
        const int c1 = 480 + quad * 8;
        const bool cv0 = (c1 + 4 <= F_IN);       // false only for quad 3
        const bool cv1 = (c1 + 8 <= F_IN);       // false for quads 2,3
        na = (vr && cv0) ? *(const float4*)&p[c1]     : z4;
        nb = (vr && cv1) ? *(const float4*)&p[c1 + 4] : z4;
        COMPUTE(14, ca, cb);
        ca = na; cb = nb;
    }
    COMPUTE(15, ca, cb);                         // tail, no prefetch

    // D layout: row = quad*4 + reg, col = lane&15 ; store bf16 * dinv[row]
#pragma unroll
    for (int reg = 0; reg < 4; ++reg) {
        int grow = rowb + quad * 4 + reg;
        if (grow < n) {
            float dv = dinv[grow];
#pragma unroll
            for (int ct = 0; ct < 4; ++ct)
                hs[(size_t)grow * HIDDEN + ct * 16 + l16] = f2bf(dv * acc[ct][reg]);
        }
    }
}

// ---------- aggregation over pre-scaled bf16 table ----------
// out[i] = dinv[i] * (sum_e hs[col[e]] + hs[i]) + b  (+ReLU or +log_softmax)
// 4 edge streams per wave (16-lane quarters), uint2 (4 bf16 feats) per lane.
// Main loop keeps 16 gathers in flight; fixed 2-step epilogue bounds the
// dependent-chain depth for the remainder (<=3 edges per stream).
template <int F, bool RELU, bool LSM>
__launch_bounds__(256)
__global__ void k_agg(const uint2* __restrict__ hs2, const int* __restrict__ rp,
                      const int* __restrict__ col, const float* __restrict__ dinv,
                      const float* __restrict__ bias, float* __restrict__ out, int n) {
    constexpr int PW2 = F / 4;     // uint2 per row (16 or 10)
    const int lane = threadIdx.x & 63;
    const int q    = lane >> 4;    // edge-stream id 0..3
    const int p    = lane & 15;    // feature-slot within stream
    const bool act = p < PW2;
    int wid = __builtin_amdgcn_readfirstlane((blockIdx.x * blockDim.x + threadIdx.x) >> 6);
    const int nw = (gridDim.x * blockDim.x) >> 6;

    for (; wid < n; wid += nw) {
        const int beg = rp[wid], end = rp[wid + 1];
        float a0 = 0.f, a1 = 0.f, a2 = 0.f, a3 = 0.f;
        int e = beg + q;
        for (; e + 12 < end; e += 16) {          // 16 edges/wave-iter, 16 gathers in flight
            int c0 = col[e], c1 = col[e + 4], c2 = col[e + 8], c3 = col[e + 12];
            uint2 v0 = act ? hs2[(unsigned)c0 * PW2 + p] : make_uint2(0u, 0u);
            uint2 v1 = act ? hs2[(unsigned)c1 * PW2 + p] : make_uint2(0u, 0u);
            uint2 v2 = act ? hs2[(unsigned)c2 * PW2 + p] : make_uint2(0u, 0u);
            uint2 v3 = act ? hs2[(unsigned)c3 * PW2 + p] : make_uint2(0u, 0u);
            a0 += bfu_lo(v0.x) + bfu_lo(v1.x) + bfu_lo(v2.x) + bfu_lo(v3.x);
            a1 += bfu_hi(v0.x) + bfu_hi(v1.x) + bfu_hi(v2.x) + bfu_hi(v3.x);
            a2 += bfu_lo(v0.y) + bfu_lo(v1.y) + bfu_lo(v2.y) + bfu_lo(v3.y);
            a3 += bfu_hi(v0.y) + bfu_hi(v1.y) + bfu_hi(v2.y) + bfu_hi(v3.y);
        }
        if (e + 4 < end) {                       // >=2 edges left in this stream
            int c0 = col[e], c1 = col[e + 4];
            uint2 v0 = act ? hs2[(unsigned)c0 * PW2 + p] : make_uint2(0u, 0u);
            uint2 v1 = act ? hs2[(unsigned)c1 * PW2 + p] : make_uint2(0u, 0u);
            a0 += bfu_lo(v0.x) + bfu_lo(v1.x);
            a1 += bfu_hi(v0.x) + bfu_hi(v1.x);
            a2 += bfu_lo(v0.y) + bfu_lo(v1.y);
            a3 += bfu_hi(v0.y) + bfu_hi(v1.y);
            e += 8;
        }
        if (e < end) {                           // last remaining edge
            int c0 = col[e];
            uint2 v0 = act ? hs2[(unsigned)c0 * PW2 + p] : make_uint2(0u, 0u);
            a0 += bfu_lo(v0.x); a1 += bfu_hi(v0.x);
            a2 += bfu_lo(v0.y); a3 += bfu_hi(v0.y);
        }
        // combine the 4 stream partials
        a0 += __shfl_xor(a0, 16); a1 += __shfl_xor(a1, 16);
        a2 += __shfl_xor(a2, 16); a3 += __shfl_xor(a3, 16);
        a0 += __shfl_xor(a0, 32); a1 += __shfl_xor(a1, 32);
        a2 += __shfl_xor(a2, 32); a3 += __shfl_xor(a3, 32);

        const float di = dinv[wid];
        uint2 sv  = act ? hs2[(unsigned)wid * PW2 + p] : make_uint2(0u, 0u);
        float4 bv = act ? *(const float4*)&bias[4 * p] : make_float4(0.f, 0.f, 0.f, 0.f);
        float r0 = di * (a0 + bfu_lo(sv.x)) + bv.x;
        float r1 = di * (a1 + bfu_hi(sv.x)) + bv.y;
        float r2 = di * (a2 + bfu_lo(sv.y)) + bv.z;
        float r3 = di * (a3 + bfu_hi(sv.y)) + bv.w;
        if (RELU) {
            r0 = fmaxf(r0, 0.f); r1 = fmaxf(r1, 0.f);
            r2 = fmaxf(r2, 0.f); r3 = fmaxf(r3, 0.f);
        }
        if (LSM) {
            float m = act ? fmaxf(fmaxf(r0, r1), fmaxf(r2, r3)) : -INFINITY;
#pragma unroll
            for (int off = 8; off; off >>= 1) m = fmaxf(m, __shfl_xor(m, off));
            float ex = act ? (__expf(r0 - m) + __expf(r1 - m) + __expf(r2 - m) + __expf(r3 - m))
                           : 0.f;
#pragma unroll
            for (int off = 8; off; off >>= 1) ex += __shfl_xor(ex, off);
            float lse = m + __logf(ex);
            r0 -= lse; r1 -= lse; r2 -= lse; r3 -= lse;
        }
        if (q == 0 && act)
            *(float4*)&out[(size_t)wid * F + 4 * p] = make_float4(r0, r1, r2, r3);
    }
}

// ---------- GEMM2: h2s[N,40](bf16, pre-scaled) = dinv * (a[N,64] @ W2[64,40]) ----------
__launch_bounds__(256)
__global__ void k_gemm2(const float* __restrict__ a, const float* __restrict__ w,
                        const float* __restrict__ dinv, unsigned short* __restrict__ out, int n) {
    __shared__ float ws[HIDDEN * N_CLASS];
    for (int idx = threadIdx.x; idx < HIDDEN * N_CLASS; idx += 256) ws[idx] = w[idx];
    __syncthreads();
    int idx = blockIdx.x * 256 + threadIdx.x;
    if (idx >= n * N_CLASS) return;
    int i = idx / N_CLASS, j = idx - i * N_CLASS;
    float s = 0.f;
#pragma unroll
    for (int k = 0; k < HIDDEN; k += 4) {
        float4 xv = *(const float4*)&a[(size_t)i * HIDDEN + k];
        s = fmaf(xv.x, ws[k * N_CLASS + j], s);
        s = fmaf(xv.y, ws[(k + 1) * N_CLASS + j], s);
        s = fmaf(xv.z, ws[(k + 2) * N_CLASS + j], s);
        s = fmaf(xv.w, ws[(k + 3) * N_CLASS + j], s);
    }
    out[idx] = f2bf(dinv[i] * s);
}

extern "C" void kernel_launch(void* const* d_in, const int* in_sizes, int n_in,
                              void* d_out, int out_size, void* d_ws, size_t ws_size,
                              hipStream_t stream) {
    const float* x   = (const float*)d_in[0];
    const float* W1  = (const float*)d_in[1];
    const float* b1  = (const float*)d_in[2];
    const float* W2  = (const float*)d_in[3];
    const float* b2  = (const float*)d_in[4];
    const int*   ei  = (const int*)d_in[5];
    const int*   src = ei;
    const int*   dst = ei + N_EDGES;
    float*       out = (float*)d_out;

    char*  ws  = (char*)d_ws;
    size_t off = 0;
    auto alloc = [&](size_t bytes) -> void* {
        void* p = ws + off;
        off += (bytes + 255) & ~(size_t)255;
        return p;
    };
    int*            bcnt = (int*)alloc((size_t)NB * 4);
    int*            bptr = (int*)alloc((size_t)(NB + 1) * 4);
    int*            bcur = (int*)alloc((size_t)NB * 4);
    int*            rp   = (int*)alloc((size_t)(N_NODES + 1) * 4);
    int*            col  = (int*)alloc((size_t)N_EDGES * 4);
    float*          dinv = (float*)alloc((size_t)N_NODES * 4);
    unsigned short* w1t  = (unsigned short*)alloc((size_t)HIDDEN * KPAD * 2);
    unsigned short* h1s  = (unsigned short*)alloc((size_t)N_NODES * HIDDEN * 2);  // bf16, pre-scaled
    float*          h1a  = (float*)alloc((size_t)N_NODES * HIDDEN * 4);           // fp32
    int2*           ebuf = (int2*)h1a;            // alias: ebuf dead before agg1 writes h1a
    unsigned short* h2s  = h1s;                   // bf16, aliases h1s (dead after agg1)

    const int NBH = (N_EDGES + EPB - 1) / EPB;   // 98

    // CSR build (bucketed counting sort) + W1^T prep (also zeroes bcnt)
    k_prep_w1t<<<(HIDDEN * KPAD + 255) / 256, 256, 0, stream>>>(W1, w1t, bcnt);
    k_bhist<<<NBH, 1024, 0, stream>>>(dst, bcnt, N_EDGES);
    k_bscan<<<1, 1024, 0, stream>>>(bcnt, bptr, bcur);
    k_bfill<<<NBH, 1024, 0, stream>>>(src, dst, bcur, ebuf, N_EDGES);
    k_bucket_csr<<<NB, 256, 0, stream>>>(ebuf, bptr, rp, col, dinv, N_NODES);

    // layer 1
    k_gemm1<<<(N_NODES + 63) / 64, 256, 0, stream>>>(x, w1t, dinv, h1s, N_NODES);
    k_agg<HIDDEN, true, false><<<2048, 256, 0, stream>>>(
        (const uint2*)h1s, rp, col, dinv, b1, h1a, N_NODES);

    // layer 2 (+fused log_softmax)
    k_gemm2<<<(N_NODES * N_CLASS + 255) / 256, 256, 0, stream>>>(h1a, W2, dinv, h2s, N_NODES);
    k_agg<N_CLASS, false, true><<<2048, 256, 0, stream>>>(
        (const uint2*)h2s, rp, col, dinv, b2, out, N_NODES);
}

// Round 5
// 523.007 us; speedup vs baseline: 1.0418x; 1.0065x over previous
//
#include <hip/hip_runtime.h>
#include <math.h>

#define N_NODES 100000
#define N_EDGES 1600000
#define F_IN    500
#define HIDDEN  64
#define N_CLASS 40
#define KPAD    512

#define NB   2048      // dst buckets
#define NPB  49        // nodes per bucket (2048*49 = 100352 >= N)
#define EPB  16384     // edges per block in bhist/bfill
#define CAP  1536      // LDS pair capacity in k_bucket_csr

typedef __attribute__((ext_vector_type(4))) float f32x4;
typedef __attribute__((ext_vector_type(8))) __bf16 bf16x8;

__device__ __forceinline__ unsigned short f2bf(float f) {
    unsigned int u = __float_as_uint(f);
    u = (u + 0x7FFF + ((u >> 16) & 1)) >> 16;   // RNE
    return (unsigned short)u;
}
__device__ __forceinline__ unsigned int packbf(float a, float b) {
    return (unsigned int)f2bf(a) | ((unsigned int)f2bf(b) << 16);
}
__device__ __forceinline__ float bfu_lo(unsigned int v) {   // low ushort -> float
    return __uint_as_float(v << 16);
}
__device__ __forceinline__ float bfu_hi(unsigned int v) {   // high ushort -> float
    return __uint_as_float(v & 0xFFFF0000u);
}

// W1t[n][k] = bf16(W1[k][n]), k zero-padded to 512; also zeroes bcnt (merged launch)
__global__ void k_prep_w1t(const float* __restrict__ w1, unsigned short* __restrict__ w1t,
                           int* __restrict__ bcnt) {
    int idx = blockIdx.x * blockDim.x + threadIdx.x;
    if (idx < NB) bcnt[idx] = 0;
    if (idx >= HIDDEN * KPAD) return;
    int n = idx >> 9, k = idx & (KPAD - 1);
    float v = (k < F_IN) ? w1[k * HIDDEN + n] : 0.f;
    w1t[idx] = f2bf(v);
}

// ---------- CSR build: bucketed counting sort ----------
__launch_bounds__(1024)
__global__ void k_bhist(const int* __restrict__ dst, int* __restrict__ bcnt, int e) {
    __shared__ int h[NB];
    for (int i = threadIdx.x; i < NB; i += 1024) h[i] = 0;
    __syncthreads();
    int base = blockIdx.x * EPB;
#pragma unroll
    for (int j = 0; j < 16; ++j) {
        int i = base + j * 1024 + threadIdx.x;
        if (i < e) atomicAdd(&h[dst[i] / NPB], 1);
    }
    __syncthreads();
    for (int i = threadIdx.x; i < NB; i += 1024)
        if (h[i]) atomicAdd(&bcnt[i], h[i]);
}

__launch_bounds__(1024)
__global__ void k_bscan(const int* __restrict__ bcnt, int* __restrict__ bptr,
                        int* __restrict__ bcur) {
    __shared__ int s[1024];
    int t = threadIdx.x;
    int a = bcnt[2 * t], b = bcnt[2 * t + 1];
    int v = a + b;
    s[t] = v;
    __syncthreads();
    for (int off = 1; off < 1024; off <<= 1) {
        int u = (t >= off) ? s[t - off] : 0;
        __syncthreads();
        s[t] += u;
        __syncthreads();
    }
    int excl = s[t] - v;
    bptr[2 * t] = excl;     bptr[2 * t + 1] = excl + a;
    bcur[2 * t] = excl;     bcur[2 * t + 1] = excl + a;
    if (t == 1023) bptr[NB] = s[1023];
}

__launch_bounds__(1024)
__global__ void k_bfill(const int* __restrict__ src, const int* __restrict__ dst,
                        int* __restrict__ bcur, int2* __restrict__ ebuf, int e) {
    __shared__ int hist[NB];
    __shared__ int base_[NB];
    for (int i = threadIdx.x; i < NB; i += 1024) hist[i] = 0;
    __syncthreads();
    int b0 = blockIdx.x * EPB;
    int s_[16], d_[16];
#pragma unroll
    for (int j = 0; j < 16; ++j) {
        int i = b0 + j * 1024 + threadIdx.x;
        if (i < e) {
            s_[j] = src[i];
            d_[j] = dst[i];
            atomicAdd(&hist[d_[j] / NPB], 1);
        } else d_[j] = -1;
    }
    __syncthreads();
    for (int i = threadIdx.x; i < NB; i += 1024) {
        int hc = hist[i];
        base_[i] = hc ? atomicAdd(&bcur[i], hc) : 0;
        hist[i] = 0;    // reuse as local cursor
    }
    __syncthreads();
#pragma unroll
    for (int j = 0; j < 16; ++j) {
        if (d_[j] >= 0) {
            int bu = d_[j] / NPB;
            int r = atomicAdd(&hist[bu], 1);
            ebuf[base_[bu] + r] = make_int2(s_[j], d_[j]);
        }
    }
}

__launch_bounds__(256)
__global__ void k_bucket_csr(const int2* __restrict__ ebuf, const int* __restrict__ bptr,
                             int* __restrict__ rp, int* __restrict__ col,
                             float* __restrict__ dinv, int n) {
    int b  = blockIdx.x;
    int lo = b * NPB;
    if (lo >= n) return;
    int hi  = min(lo + NPB, n);
    int eb0 = bptr[b], ec = bptr[b + 1] - eb0;

    __shared__ int2 pairs[CAP];
    __shared__ int  hist[NPB];
    __shared__ int  excl[NPB + 1];
    for (int j = threadIdx.x; j < NPB; j += 256) hist[j] = 0;
    __syncthreads();
    for (int i = threadIdx.x; i < ec; i += 256) {
        int2 p = ebuf[eb0 + i];
        if (i < CAP) pairs[i] = p;
        atomicAdd(&hist[p.y - lo], 1);
    }
    __syncthreads();
    if (threadIdx.x == 0) {
        int acc = 0;
        for (int j = 0; j < NPB; ++j) { excl[j] = acc; acc += hist[j]; }
        excl[NPB] = acc;
    }
    __syncthreads();
    for (int j = threadIdx.x; j < hi - lo; j += 256) {
        rp[lo + j]   = eb0 + excl[j];
        dinv[lo + j] = rsqrtf((float)(hist[j] + 1));   // +1 self loop
    }
    if (hi == n && threadIdx.x == 0) rp[n] = eb0 + ec;
    __syncthreads();
    for (int j = threadIdx.x; j < NPB; j += 256) hist[j] = 0;  // reuse as cursor
    __syncthreads();
    for (int i = threadIdx.x; i < ec; i += 256) {
        int2 p  = (i < CAP) ? pairs[i] : ebuf[eb0 + i];
        int  li = p.y - lo;
        int  r  = atomicAdd(&hist[li], 1);
        col[eb0 + excl[li] + r] = p.x;
    }
}

// ---------- GEMM1: hs[N,64](bf16, pre-scaled by dinv) = dinv * (x @ W1) ----------
// v4: W1^T staged into LDS once per block (rows padded +16B -> 2-way bank
// aliasing only). bfrag reads become ds_read_b128 on lgkmcnt, so the MFMA's
// wait no longer drains the x-load vmcnt queue. x slices use a depth-3
// register pipeline (fully unrolled K-loop -> static %3 indices).
__launch_bounds__(512)
__global__ void k_gemm1(const float* __restrict__ x, const unsigned short* __restrict__ w1t,
                        const float* __restrict__ dinv, unsigned short* __restrict__ hs, int n) {
    constexpr int LDW = 520;                       // 512 + 8 ushorts (16B pad)
    __shared__ __align__(16) unsigned short w1l[HIDDEN * LDW];   // 66,560 B

    const int tid  = threadIdx.x;
    const int wave = tid >> 6;
    const int lane = tid & 63;
    const int quad = lane >> 4;
    const int l16  = lane & 15;

    // stage W1^T into LDS (once): 4096 16B-chunks, 64 per row, coalesced reads
    {
        const uint4* g = (const uint4*)w1t;
#pragma unroll
        for (int i = 0; i < 8; ++i) {
            int c   = i * 512 + tid;
            int row = c >> 6, cc = c & 63;
            uint4 v = g[c];
            *(uint4*)&w1l[row * LDW + cc * 8] = v;
        }
    }
    __syncthreads();

    const int rowb = blockIdx.x * 128 + wave * 16;
    const int  row = rowb + l16;
    const bool vr  = row < n;
    const float* p = &x[(size_t)(vr ? row : 0) * F_IN];
    const float4 z4 = make_float4(0.f, 0.f, 0.f, 0.f);

    f32x4 acc[4];
#pragma unroll
    for (int ct = 0; ct < 4; ++ct) acc[ct] = (f32x4)0.f;

    float4 xa[3], xb[3];
    auto XLOAD = [&](int ks) {
        const int c0 = ks * 32 + quad * 8;
        if (ks < 15) {
            xa[ks % 3] = vr ? *(const float4*)&p[c0]     : z4;
            xb[ks % 3] = vr ? *(const float4*)&p[c0 + 4] : z4;
        } else {
            const bool cv0 = (c0 + 4 <= F_IN);     // false only for quad 3
            const bool cv1 = (c0 + 8 <= F_IN);     // false for quads 2,3
            xa[ks % 3] = (vr && cv0) ? *(const float4*)&p[c0]     : z4;
            xb[ks % 3] = (vr && cv1) ? *(const float4*)&p[c0 + 4] : z4;
        }
    };
    XLOAD(0); XLOAD(1); XLOAD(2);

#pragma unroll
    for (int ks = 0; ks < 16; ++ks) {
        bf16x8 bfrag[4];
#pragma unroll
        for (int ct = 0; ct < 4; ++ct)
            bfrag[ct] = *(const bf16x8*)&w1l[(ct * 16 + l16) * LDW + ks * 32 + quad * 8];
        const float4 ca = xa[ks % 3];
        const float4 cb = xb[ks % 3];
        if (ks + 3 < 16) XLOAD(ks + 3);            // keep 3 slices (6 loads) in flight
        union { bf16x8 v; unsigned int u[4]; } af;
        af.u[0] = packbf(ca.x, ca.y); af.u[1] = packbf(ca.z, ca.w);
        af.u[2] = packbf(cb.x, cb.y); af.u[3] = packbf(cb.z, cb.w);
#pragma unroll
        for (int ct = 0; ct < 4; ++ct)
            acc[ct] = __builtin_amdgcn_mfma_f32_16x16x32_bf16(af.v, bfrag[ct], acc[ct], 0, 0, 0);
    }

    // D layout: row = quad*4 + reg, col = lane&15 ; store bf16 * dinv[row]
#pragma unroll
    for (int reg = 0; reg < 4; ++reg) {
        int grow = rowb + quad * 4 + reg;
        if (grow < n) {
            float dv = dinv[grow];
#pragma unroll
            for (int ct = 0; ct < 4; ++ct)
                hs[(size_t)grow * HIDDEN + ct * 16 + l16] = f2bf(dv * acc[ct][reg]);
        }
    }
}

// ---------- aggregation over pre-scaled bf16 table ----------
// out[i] = dinv[i] * (sum_e hs[col[e]] + hs[i]) + b  (+ReLU or +log_softmax)
// 4 edge streams per wave (16-lane quarters), uint2 (4 bf16 feats) per lane.
// Main loop keeps 16 gathers in flight; fixed 2-step epilogue bounds the
// dependent-chain depth for the remainder (<=3 edges per stream).
template <int F, bool RELU, bool LSM>
__launch_bounds__(256)
__global__ void k_agg(const uint2* __restrict__ hs2, const int* __restrict__ rp,
                      const int* __restrict__ col, const float* __restrict__ dinv,
                      const float* __restrict__ bias, float* __restrict__ out, int n) {
    constexpr int PW2 = F / 4;     // uint2 per row (16 or 10)
    const int lane = threadIdx.x & 63;
    const int q    = lane >> 4;    // edge-stream id 0..3
    const int p    = lane & 15;    // feature-slot within stream
    const bool act = p < PW2;
    int wid = __builtin_amdgcn_readfirstlane((blockIdx.x * blockDim.x + threadIdx.x) >> 6);
    const int nw = (gridDim.x * blockDim.x) >> 6;

    for (; wid < n; wid += nw) {
        const int beg = rp[wid], end = rp[wid + 1];
        float a0 = 0.f, a1 = 0.f, a2 = 0.f, a3 = 0.f;
        int e = beg + q;
        for (; e + 12 < end; e += 16) {          // 16 edges/wave-iter, 16 gathers in flight
            int c0 = col[e], c1 = col[e + 4], c2 = col[e + 8], c3 = col[e + 12];
            uint2 v0 = act ? hs2[(unsigned)c0 * PW2 + p] : make_uint2(0u, 0u);
            uint2 v1 = act ? hs2[(unsigned)c1 * PW2 + p] : make_uint2(0u, 0u);
            uint2 v2 = act ? hs2[(unsigned)c2 * PW2 + p] : make_uint2(0u, 0u);
            uint2 v3 = act ? hs2[(unsigned)c3 * PW2 + p] : make_uint2(0u, 0u);
            a0 += bfu_lo(v0.x) + bfu_lo(v1.x) + bfu_lo(v2.x) + bfu_lo(v3.x);
            a1 += bfu_hi(v0.x) + bfu_hi(v1.x) + bfu_hi(v2.x) + bfu_hi(v3.x);
            a2 += bfu_lo(v0.y) + bfu_lo(v1.y) + bfu_lo(v2.y) + bfu_lo(v3.y);
            a3 += bfu_hi(v0.y) + bfu_hi(v1.y) + bfu_hi(v2.y) + bfu_hi(v3.y);
        }
        if (e + 4 < end) {                       // >=2 edges left in this stream
            int c0 = col[e], c1 = col[e + 4];
            uint2 v0 = act ? hs2[(unsigned)c0 * PW2 + p] : make_uint2(0u, 0u);
            uint2 v1 = act ? hs2[(unsigned)c1 * PW2 + p] : make_uint2(0u, 0u);
            a0 += bfu_lo(v0.x) + bfu_lo(v1.x);
            a1 += bfu_hi(v0.x) + bfu_hi(v1.x);
            a2 += bfu_lo(v0.y) + bfu_lo(v1.y);
            a3 += bfu_hi(v0.y) + bfu_hi(v1.y);
            e += 8;
        }
        if (e < end) {                           // last remaining edge
            int c0 = col[e];
            uint2 v0 = act ? hs2[(unsigned)c0 * PW2 + p] : make_uint2(0u, 0u);
            a0 += bfu_lo(v0.x); a1 += bfu_hi(v0.x);
            a2 += bfu_lo(v0.y); a3 += bfu_hi(v0.y);
        }
        // combine the 4 stream partials
        a0 += __shfl_xor(a0, 16); a1 += __shfl_xor(a1, 16);
        a2 += __shfl_xor(a2, 16); a3 += __shfl_xor(a3, 16);
        a0 += __shfl_xor(a0, 32); a1 += __shfl_xor(a1, 32);
        a2 += __shfl_xor(a2, 32); a3 += __shfl_xor(a3, 32);

        const float di = dinv[wid];
        uint2 sv  = act ? hs2[(unsigned)wid * PW2 + p] : make_uint2(0u, 0u);
        float4 bv = act ? *(const float4*)&bias[4 * p] : make_float4(0.f, 0.f, 0.f, 0.f);
        float r0 = di * (a0 + bfu_lo(sv.x)) + bv.x;
        float r1 = di * (a1 + bfu_hi(sv.x)) + bv.y;
        float r2 = di * (a2 + bfu_lo(sv.y)) + bv.z;
        float r3 = di * (a3 + bfu_hi(sv.y)) + bv.w;
        if (RELU) {
            r0 = fmaxf(r0, 0.f); r1 = fmaxf(r1, 0.f);
            r2 = fmaxf(r2, 0.f); r3 = fmaxf(r3, 0.f);
        }
        if (LSM) {
            float m = act ? fmaxf(fmaxf(r0, r1), fmaxf(r2, r3)) : -INFINITY;
#pragma unroll
            for (int off = 8; off; off >>= 1) m = fmaxf(m, __shfl_xor(m, off));
            float ex = act ? (__expf(r0 - m) + __expf(r1 - m) + __expf(r2 - m) + __expf(r3 - m))
                           : 0.f;
#pragma unroll
            for (int off = 8; off; off >>= 1) ex += __shfl_xor(ex, off);
            float lse = m + __logf(ex);
            r0 -= lse; r1 -= lse; r2 -= lse; r3 -= lse;
        }
        if (q == 0 && act)
            *(float4*)&out[(size_t)wid * F + 4 * p] = make_float4(r0, r1, r2, r3);
    }
}

// ---------- GEMM2: h2s[N,40](bf16, pre-scaled) = dinv * (a[N,64] @ W2[64,40]) ----------
__launch_bounds__(256)
__global__ void k_gemm2(const float* __restrict__ a, const float* __restrict__ w,
                        const float* __restrict__ dinv, unsigned short* __restrict__ out, int n) {
    __shared__ float ws[HIDDEN * N_CLASS];
    for (int idx = threadIdx.x; idx < HIDDEN * N_CLASS; idx += 256) ws[idx] = w[idx];
    __syncthreads();
    int idx = blockIdx.x * 256 + threadIdx.x;
    if (idx >= n * N_CLASS) return;
    int i = idx / N_CLASS, j = idx - i * N_CLASS;
    float s = 0.f;
#pragma unroll
    for (int k = 0; k < HIDDEN; k += 4) {
        float4 xv = *(const float4*)&a[(size_t)i * HIDDEN + k];
        s = fmaf(xv.x, ws[k * N_CLASS + j], s);
        s = fmaf(xv.y, ws[(k + 1) * N_CLASS + j], s);
        s = fmaf(xv.z, ws[(k + 2) * N_CLASS + j], s);
        s = fmaf(xv.w, ws[(k + 3) * N_CLASS + j], s);
    }
    out[idx] = f2bf(dinv[i] * s);
}

extern "C" void kernel_launch(void* const* d_in, const int* in_sizes, int n_in,
                              void* d_out, int out_size, void* d_ws, size_t ws_size,
                              hipStream_t stream) {
    const float* x   = (const float*)d_in[0];
    const float* W1  = (const float*)d_in[1];
    const float* b1  = (const float*)d_in[2];
    const float* W2  = (const float*)d_in[3];
    const float* b2  = (const float*)d_in[4];
    const int*   ei  = (const int*)d_in[5];
    const int*   src = ei;
    const int*   dst = ei + N_EDGES;
    float*       out = (float*)d_out;

    char*  ws  = (char*)d_ws;
    size_t off = 0;
    auto alloc = [&](size_t bytes) -> void* {
        void* p = ws + off;
        off += (bytes + 255) & ~(size_t)255;
        return p;
    };
    int*            bcnt = (int*)alloc((size_t)NB * 4);
    int*            bptr = (int*)alloc((size_t)(NB + 1) * 4);
    int*            bcur = (int*)alloc((size_t)NB * 4);
    int*            rp   = (int*)alloc((size_t)(N_NODES + 1) * 4);
    int*            col  = (int*)alloc((size_t)N_EDGES * 4);
    float*          dinv = (float*)alloc((size_t)N_NODES * 4);
    unsigned short* w1t  = (unsigned short*)alloc((size_t)HIDDEN * KPAD * 2);
    unsigned short* h1s  = (unsigned short*)alloc((size_t)N_NODES * HIDDEN * 2);  // bf16, pre-scaled
    float*          h1a  = (float*)alloc((size_t)N_NODES * HIDDEN * 4);           // fp32
    int2*           ebuf = (int2*)h1a;            // alias: ebuf dead before agg1 writes h1a
    unsigned short* h2s  = h1s;                   // bf16, aliases h1s (dead after agg1)

    const int NBH = (N_EDGES + EPB - 1) / EPB;   // 98

    // CSR build (bucketed counting sort) + W1^T prep (also zeroes bcnt)
    k_prep_w1t<<<(HIDDEN * KPAD + 255) / 256, 256, 0, stream>>>(W1, w1t, bcnt);
    k_bhist<<<NBH, 1024, 0, stream>>>(dst, bcnt, N_EDGES);
    k_bscan<<<1, 1024, 0, stream>>>(bcnt, bptr, bcur);
    k_bfill<<<NBH, 1024, 0, stream>>>(src, dst, bcur, ebuf, N_EDGES);
    k_bucket_csr<<<NB, 256, 0, stream>>>(ebuf, bptr, rp, col, dinv, N_NODES);

    // layer 1
    k_gemm1<<<(N_NODES + 127) / 128, 512, 0, stream>>>(x, w1t, dinv, h1s, N_NODES);
    k_agg<HIDDEN, true, false><<<2048, 256, 0, stream>>>(
        (const uint2*)h1s, rp, col, dinv, b1, h1a, N_NODES);

    // layer 2 (+fused log_softmax)
    k_gemm2<<<(N_NODES * N_CLASS + 255) / 256, 256, 0, stream>>>(h1a, W2, dinv, h2s, N_NODES);
    k_agg<N_CLASS, false, true><<<2048, 256, 0, stream>>>(
        (const uint2*)h2s, rp, col, dinv, b2, out, N_NODES);
}

// Round 6
// 514.217 us; speedup vs baseline: 1.0596x; 1.0171x over previous
//
#include <hip/hip_runtime.h>
#include <math.h>

#define N_NODES 100000
#define N_EDGES 1600000
#define F_IN    500
#define HIDDEN  64
#define N_CLASS 40
#define KPAD    512

#define NB   2048      // dst buckets
#define NPB  49        // nodes per bucket (2048*49 = 100352 >= N)
#define EPB  16384     // edges per block in bhist/bfill
#define CAP  1536      // LDS pair capacity in k_bucket_csr

typedef __attribute__((ext_vector_type(4))) float f32x4;
typedef __attribute__((ext_vector_type(8))) __bf16 bf16x8;

__device__ __forceinline__ unsigned short f2bf(float f) {
    unsigned int u = __float_as_uint(f);
    u = (u + 0x7FFF + ((u >> 16) & 1)) >> 16;   // RNE
    return (unsigned short)u;
}
__device__ __forceinline__ unsigned int packbf(float a, float b) {
    return (unsigned int)f2bf(a) | ((unsigned int)f2bf(b) << 16);
}
__device__ __forceinline__ float bfu_lo(unsigned int v) {   // low ushort -> float
    return __uint_as_float(v << 16);
}
__device__ __forceinline__ float bfu_hi(unsigned int v) {   // high ushort -> float
    return __uint_as_float(v & 0xFFFF0000u);
}

// W1t[n][k] = bf16(W1[k][n]), k zero-padded to 512; also zeroes bcnt (merged launch)
__global__ void k_prep_w1t(const float* __restrict__ w1, unsigned short* __restrict__ w1t,
                           int* __restrict__ bcnt) {
    int idx = blockIdx.x * blockDim.x + threadIdx.x;
    if (idx < NB) bcnt[idx] = 0;
    if (idx >= HIDDEN * KPAD) return;
    int n = idx >> 9, k = idx & (KPAD - 1);
    float v = (k < F_IN) ? w1[k * HIDDEN + n] : 0.f;
    w1t[idx] = f2bf(v);
}

// ---------- CSR build: bucketed counting sort ----------
__launch_bounds__(1024)
__global__ void k_bhist(const int* __restrict__ dst, int* __restrict__ bcnt, int e) {
    __shared__ int h[NB];
    for (int i = threadIdx.x; i < NB; i += 1024) h[i] = 0;
    __syncthreads();
    int base = blockIdx.x * EPB;
#pragma unroll
    for (int j = 0; j < 16; ++j) {
        int i = base + j * 1024 + threadIdx.x;
        if (i < e) atomicAdd(&h[dst[i] / NPB], 1);
    }
    __syncthreads();
    for (int i = threadIdx.x; i < NB; i += 1024)
        if (h[i]) atomicAdd(&bcnt[i], h[i]);
}

__launch_bounds__(1024)
__global__ void k_bscan(const int* __restrict__ bcnt, int* __restrict__ bptr,
                        int* __restrict__ bcur) {
    __shared__ int s[1024];
    int t = threadIdx.x;
    int a = bcnt[2 * t], b = bcnt[2 * t + 1];
    int v = a + b;
    s[t] = v;
    __syncthreads();
    for (int off = 1; off < 1024; off <<= 1) {
        int u = (t >= off) ? s[t - off] : 0;
        __syncthreads();
        s[t] += u;
        __syncthreads();
    }
    int excl = s[t] - v;
    bptr[2 * t] = excl;     bptr[2 * t + 1] = excl + a;
    bcur[2 * t] = excl;     bcur[2 * t + 1] = excl + a;
    if (t == 1023) bptr[NB] = s[1023];
}

__launch_bounds__(1024)
__global__ void k_bfill(const int* __restrict__ src, const int* __restrict__ dst,
                        int* __restrict__ bcur, int2* __restrict__ ebuf, int e) {
    __shared__ int hist[NB];
    __shared__ int base_[NB];
    for (int i = threadIdx.x; i < NB; i += 1024) hist[i] = 0;
    __syncthreads();
    int b0 = blockIdx.x * EPB;
    int s_[16], d_[16];
#pragma unroll
    for (int j = 0; j < 16; ++j) {
        int i = b0 + j * 1024 + threadIdx.x;
        if (i < e) {
            s_[j] = src[i];
            d_[j] = dst[i];
            atomicAdd(&hist[d_[j] / NPB], 1);
        } else d_[j] = -1;
    }
    __syncthreads();
    for (int i = threadIdx.x; i < NB; i += 1024) {
        int hc = hist[i];
        base_[i] = hc ? atomicAdd(&bcur[i], hc) : 0;
        hist[i] = 0;    // reuse as local cursor
    }
    __syncthreads();
#pragma unroll
    for (int j = 0; j < 16; ++j) {
        if (d_[j] >= 0) {
            int bu = d_[j] / NPB;
            int r = atomicAdd(&hist[bu], 1);
            ebuf[base_[bu] + r] = make_int2(s_[j], d_[j]);
        }
    }
}

__launch_bounds__(256)
__global__ void k_bucket_csr(const int2* __restrict__ ebuf, const int* __restrict__ bptr,
                             int* __restrict__ rp, int* __restrict__ col,
                             float* __restrict__ dinv, int n) {
    int b  = blockIdx.x;
    int lo = b * NPB;
    if (lo >= n) return;
    int hi  = min(lo + NPB, n);
    int eb0 = bptr[b], ec = bptr[b + 1] - eb0;

    __shared__ int2 pairs[CAP];
    __shared__ int  hist[NPB];
    __shared__ int  excl[NPB + 1];
    for (int j = threadIdx.x; j < NPB; j += 256) hist[j] = 0;
    __syncthreads();
    for (int i = threadIdx.x; i < ec; i += 256) {
        int2 p = ebuf[eb0 + i];
        if (i < CAP) pairs[i] = p;
        atomicAdd(&hist[p.y - lo], 1);
    }
    __syncthreads();
    if (threadIdx.x == 0) {
        int acc = 0;
        for (int j = 0; j < NPB; ++j) { excl[j] = acc; acc += hist[j]; }
        excl[NPB] = acc;
    }
    __syncthreads();
    for (int j = threadIdx.x; j < hi - lo; j += 256) {
        rp[lo + j]   = eb0 + excl[j];
        dinv[lo + j] = rsqrtf((float)(hist[j] + 1));   // +1 self loop
    }
    if (hi == n && threadIdx.x == 0) rp[n] = eb0 + ec;
    __syncthreads();
    for (int j = threadIdx.x; j < NPB; j += 256) hist[j] = 0;  // reuse as cursor
    __syncthreads();
    for (int i = threadIdx.x; i < ec; i += 256) {
        int2 p  = (i < CAP) ? pairs[i] : ebuf[eb0 + i];
        int  li = p.y - lo;
        int  r  = atomicAdd(&hist[li], 1);
        col[eb0 + excl[li] + r] = p.x;
    }
}

// ---------- GEMM1: hs[N,64](bf16, pre-scaled by dinv) = dinv * (x @ W1) ----------
// v5: same as v4 (W1^T LDS-resident, bfrag on lgkmcnt) but x register pipeline
// deepened 3 -> 8: prologue issues 16 loads, steady state keeps ~14 in flight
// (vmcnt(14) waits). Outstanding bytes/CU ~4 KB vs the ~6 KB Little's-law
// target for the 32 us floor.
__launch_bounds__(512)
__global__ void k_gemm1(const float* __restrict__ x, const unsigned short* __restrict__ w1t,
                        const float* __restrict__ dinv, unsigned short* __restrict__ hs, int n) {
    constexpr int LDW = 520;                       // 512 + 8 ushorts (16B pad)
    __shared__ __align__(16) unsigned short w1l[HIDDEN * LDW];   // 66,560 B

    const int tid  = threadIdx.x;
    const int wave = tid >> 6;
    const int lane = tid & 63;
    const int quad = lane >> 4;
    const int l16  = lane & 15;

    // stage W1^T into LDS (once): 4096 16B-chunks, 64 per row, coalesced reads
    {
        const uint4* g = (const uint4*)w1t;
#pragma unroll
        for (int i = 0; i < 8; ++i) {
            int c   = i * 512 + tid;
            int row = c >> 6, cc = c & 63;
            uint4 v = g[c];
            *(uint4*)&w1l[row * LDW + cc * 8] = v;
        }
    }
    __syncthreads();

    const int rowb = blockIdx.x * 128 + wave * 16;
    const int  row = rowb + l16;
    const bool vr  = row < n;
    const float* p = &x[(size_t)(vr ? row : 0) * F_IN];
    const float4 z4 = make_float4(0.f, 0.f, 0.f, 0.f);

    f32x4 acc[4];
#pragma unroll
    for (int ct = 0; ct < 4; ++ct) acc[ct] = (f32x4)0.f;

    float4 xa[8], xb[8];
    auto XLOAD = [&](int ks) {
        const int c0 = ks * 32 + quad * 8;
        if (ks < 15) {
            xa[ks % 8] = vr ? *(const float4*)&p[c0]     : z4;
            xb[ks % 8] = vr ? *(const float4*)&p[c0 + 4] : z4;
        } else {
            const bool cv0 = (c0 + 4 <= F_IN);     // false only for quad 3
            const bool cv1 = (c0 + 8 <= F_IN);     // false for quads 2,3
            xa[ks % 8] = (vr && cv0) ? *(const float4*)&p[c0]     : z4;
            xb[ks % 8] = (vr && cv1) ? *(const float4*)&p[c0 + 4] : z4;
        }
    };
#pragma unroll
    for (int ks = 0; ks < 8; ++ks) XLOAD(ks);      // 16 loads issued back-to-back

#pragma unroll
    for (int ks = 0; ks < 16; ++ks) {
        bf16x8 bfrag[4];
#pragma unroll
        for (int ct = 0; ct < 4; ++ct)
            bfrag[ct] = *(const bf16x8*)&w1l[(ct * 16 + l16) * LDW + ks * 32 + quad * 8];
        const float4 ca = xa[ks % 8];
        const float4 cb = xb[ks % 8];
        if (ks + 8 < 16) XLOAD(ks + 8);            // keep ~14 loads in flight
        union { bf16x8 v; unsigned int u[4]; } af;
        af.u[0] = packbf(ca.x, ca.y); af.u[1] = packbf(ca.z, ca.w);
        af.u[2] = packbf(cb.x, cb.y); af.u[3] = packbf(cb.z, cb.w);
#pragma unroll
        for (int ct = 0; ct < 4; ++ct)
            acc[ct] = __builtin_amdgcn_mfma_f32_16x16x32_bf16(af.v, bfrag[ct], acc[ct], 0, 0, 0);
    }

    // D layout: row = quad*4 + reg, col = lane&15 ; store bf16 * dinv[row]
#pragma unroll
    for (int reg = 0; reg < 4; ++reg) {
        int grow = rowb + quad * 4 + reg;
        if (grow < n) {
            float dv = dinv[grow];
#pragma unroll
            for (int ct = 0; ct < 4; ++ct)
                hs[(size_t)grow * HIDDEN + ct * 16 + l16] = f2bf(dv * acc[ct][reg]);
        }
    }
}

// ---------- aggregation over pre-scaled bf16 table ----------
// out[i] = dinv[i] * (sum_e hs[col[e]] + hs[i]) + b  (+ReLU or +log_softmax)
// 4 edge streams per wave (16-lane quarters), uint2 (4 bf16 feats) per lane.
// Main loop keeps 16 gathers in flight; fixed 2-step epilogue bounds the
// dependent-chain depth for the remainder (<=3 edges per stream).
template <int F, bool RELU, bool LSM>
__launch_bounds__(256)
__global__ void k_agg(const uint2* __restrict__ hs2, const int* __restrict__ rp,
                      const int* __restrict__ col, const float* __restrict__ dinv,
                      const float* __restrict__ bias, float* __restrict__ out, int n) {
    constexpr int PW2 = F / 4;     // uint2 per row (16 or 10)
    const int lane = threadIdx.x & 63;
    const int q    = lane >> 4;    // edge-stream id 0..3
    const int p    = lane & 15;    // feature-slot within stream
    const bool act = p < PW2;
    int wid = __builtin_amdgcn_readfirstlane((blockIdx.x * blockDim.x + threadIdx.x) >> 6);
    const int nw = (gridDim.x * blockDim.x) >> 6;

    for (; wid < n; wid += nw) {
        const int beg = rp[wid], end = rp[wid + 1];
        float a0 = 0.f, a1 = 0.f, a2 = 0.f, a3 = 0.f;
        int e = beg + q;
        for (; e + 12 < end; e += 16) {          // 16 edges/wave-iter, 16 gathers in flight
            int c0 = col[e], c1 = col[e + 4], c2 = col[e + 8], c3 = col[e + 12];
            uint2 v0 = act ? hs2[(unsigned)c0 * PW2 + p] : make_uint2(0u, 0u);
            uint2 v1 = act ? hs2[(unsigned)c1 * PW2 + p] : make_uint2(0u, 0u);
            uint2 v2 = act ? hs2[(unsigned)c2 * PW2 + p] : make_uint2(0u, 0u);
            uint2 v3 = act ? hs2[(unsigned)c3 * PW2 + p] : make_uint2(0u, 0u);
            a0 += bfu_lo(v0.x) + bfu_lo(v1.x) + bfu_lo(v2.x) + bfu_lo(v3.x);
            a1 += bfu_hi(v0.x) + bfu_hi(v1.x) + bfu_hi(v2.x) + bfu_hi(v3.x);
            a2 += bfu_lo(v0.y) + bfu_lo(v1.y) + bfu_lo(v2.y) + bfu_lo(v3.y);
            a3 += bfu_hi(v0.y) + bfu_hi(v1.y) + bfu_hi(v2.y) + bfu_hi(v3.y);
        }
        if (e + 4 < end) {                       // >=2 edges left in this stream
            int c0 = col[e], c1 = col[e + 4];
            uint2 v0 = act ? hs2[(unsigned)c0 * PW2 + p] : make_uint2(0u, 0u);
            uint2 v1 = act ? hs2[(unsigned)c1 * PW2 + p] : make_uint2(0u, 0u);
            a0 += bfu_lo(v0.x) + bfu_lo(v1.x);
            a1 += bfu_hi(v0.x) + bfu_hi(v1.x);
            a2 += bfu_lo(v0.y) + bfu_lo(v1.y);
            a3 += bfu_hi(v0.y) + bfu_hi(v1.y);
            e += 8;
        }
        if (e < end) {                           // last remaining edge
            int c0 = col[e];
            uint2 v0 = act ? hs2[(unsigned)c0 * PW2 + p] : make_uint2(0u, 0u);
            a0 += bfu_lo(v0.x); a1 += bfu_hi(v0.x);
            a2 += bfu_lo(v0.y); a3 += bfu_hi(v0.y);
        }
        // combine the 4 stream partials
        a0 += __shfl_xor(a0, 16); a1 += __shfl_xor(a1, 16);
        a2 += __shfl_xor(a2, 16); a3 += __shfl_xor(a3, 16);
        a0 += __shfl_xor(a0, 32); a1 += __shfl_xor(a1, 32);
        a2 += __shfl_xor(a2, 32); a3 += __shfl_xor(a3, 32);

        const float di = dinv[wid];
        uint2 sv  = act ? hs2[(unsigned)wid * PW2 + p] : make_uint2(0u, 0u);
        float4 bv = act ? *(const float4*)&bias[4 * p] : make_float4(0.f, 0.f, 0.f, 0.f);
        float r0 = di * (a0 + bfu_lo(sv.x)) + bv.x;
        float r1 = di * (a1 + bfu_hi(sv.x)) + bv.y;
        float r2 = di * (a2 + bfu_lo(sv.y)) + bv.z;
        float r3 = di * (a3 + bfu_hi(sv.y)) + bv.w;
        if (RELU) {
            r0 = fmaxf(r0, 0.f); r1 = fmaxf(r1, 0.f);
            r2 = fmaxf(r2, 0.f); r3 = fmaxf(r3, 0.f);
        }
        if (LSM) {
            float m = act ? fmaxf(fmaxf(r0, r1), fmaxf(r2, r3)) : -INFINITY;
#pragma unroll
            for (int off = 8; off; off >>= 1) m = fmaxf(m, __shfl_xor(m, off));
            float ex = act ? (__expf(r0 - m) + __expf(r1 - m) + __expf(r2 - m) + __expf(r3 - m))
                           : 0.f;
#pragma unroll
            for (int off = 8; off; off >>= 1) ex += __shfl_xor(ex, off);
            float lse = m + __logf(ex);
            r0 -= lse; r1 -= lse; r2 -= lse; r3 -= lse;
        }
        if (q == 0 && act)
            *(float4*)&out[(size_t)wid * F + 4 * p] = make_float4(r0, r1, r2, r3);
    }
}

// ---------- GEMM2: h2s[N,40](bf16, pre-scaled) = dinv * (a[N,64] @ W2[64,40]) ----------
__launch_bounds__(256)
__global__ void k_gemm2(const float* __restrict__ a, const float* __restrict__ w,
                        const float* __restrict__ dinv, unsigned short* __restrict__ out, int n) {
    __shared__ float ws[HIDDEN * N_CLASS];
    for (int idx = threadIdx.x; idx < HIDDEN * N_CLASS; idx += 256) ws[idx] = w[idx];
    __syncthreads();
    int idx = blockIdx.x * 256 + threadIdx.x;
    if (idx >= n * N_CLASS) return;
    int i = idx / N_CLASS, j = idx - i * N_CLASS;
    float s = 0.f;
#pragma unroll
    for (int k = 0; k < HIDDEN; k += 4) {
        float4 xv = *(const float4*)&a[(size_t)i * HIDDEN + k];
        s = fmaf(xv.x, ws[k * N_CLASS + j], s);
        s = fmaf(xv.y, ws[(k + 1) * N_CLASS + j], s);
        s = fmaf(xv.z, ws[(k + 2) * N_CLASS + j], s);
        s = fmaf(xv.w, ws[(k + 3) * N_CLASS + j], s);
    }
    out[idx] = f2bf(dinv[i] * s);
}

extern "C" void kernel_launch(void* const* d_in, const int* in_sizes, int n_in,
                              void* d_out, int out_size, void* d_ws, size_t ws_size,
                              hipStream_t stream) {
    const float* x   = (const float*)d_in[0];
    const float* W1  = (const float*)d_in[1];
    const float* b1  = (const float*)d_in[2];
    const float* W2  = (const float*)d_in[3];
    const float* b2  = (const float*)d_in[4];
    const int*   ei  = (const int*)d_in[5];
    const int*   src = ei;
    const int*   dst = ei + N_EDGES;
    float*       out = (float*)d_out;

    char*  ws  = (char*)d_ws;
    size_t off = 0;
    auto alloc = [&](size_t bytes) -> void* {
        void* p = ws + off;
        off += (bytes + 255) & ~(size_t)255;
        return p;
    };
    int*            bcnt = (int*)alloc((size_t)NB * 4);
    int*            bptr = (int*)alloc((size_t)(NB + 1) * 4);
    int*            bcur = (int*)alloc((size_t)NB * 4);
    int*            rp   = (int*)alloc((size_t)(N_NODES + 1) * 4);
    int*            col  = (int*)alloc((size_t)N_EDGES * 4);
    float*          dinv = (float*)alloc((size_t)N_NODES * 4);
    unsigned short* w1t  = (unsigned short*)alloc((size_t)HIDDEN * KPAD * 2);
    unsigned short* h1s  = (unsigned short*)alloc((size_t)N_NODES * HIDDEN * 2);  // bf16, pre-scaled
    float*          h1a  = (float*)alloc((size_t)N_NODES * HIDDEN * 4);           // fp32
    int2*           ebuf = (int2*)h1a;            // alias: ebuf dead before agg1 writes h1a
    unsigned short* h2s  = h1s;                   // bf16, aliases h1s (dead after agg1)

    const int NBH = (N_EDGES + EPB - 1) / EPB;   // 98

    // CSR build (bucketed counting sort) + W1^T prep (also zeroes bcnt)
    k_prep_w1t<<<(HIDDEN * KPAD + 255) / 256, 256, 0, stream>>>(W1, w1t, bcnt);
    k_bhist<<<NBH, 1024, 0, stream>>>(dst, bcnt, N_EDGES);
    k_bscan<<<1, 1024, 0, stream>>>(bcnt, bptr, bcur);
    k_bfill<<<NBH, 1024, 0, stream>>>(src, dst, bcur, ebuf, N_EDGES);
    k_bucket_csr<<<NB, 256, 0, stream>>>(ebuf, bptr, rp, col, dinv, N_NODES);

    // layer 1
    k_gemm1<<<(N_NODES + 127) / 128, 512, 0, stream>>>(x, w1t, dinv, h1s, N_NODES);
    k_agg<HIDDEN, true, false><<<2048, 256, 0, stream>>>(
        (const uint2*)h1s, rp, col, dinv, b1, h1a, N_NODES);

    // layer 2 (+fused log_softmax)
    k_gemm2<<<(N_NODES * N_CLASS + 255) / 256, 256, 0, stream>>>(h1a, W2, dinv, h2s, N_NODES);
    k_agg<N_CLASS, false, true><<<2048, 256, 0, stream>>>(
        (const uint2*)h2s, rp, col, dinv, b2, out, N_NODES);
}

// Round 7
// 486.950 us; speedup vs baseline: 1.1190x; 1.0560x over previous
//
#include <hip/hip_runtime.h>
#include <math.h>

#define N_NODES 100000
#define N_EDGES 1600000
#define F_IN    500
#define HIDDEN  64
#define N_CLASS 40
#define KPAD    512

#define NB   2048      // dst buckets
#define NPB  49        // nodes per bucket (2048*49 = 100352 >= N)
#define EPB  16384     // edges per block in bhist/bfill
#define CAP  1536      // LDS pair capacity in k_bucket_csr

typedef __attribute__((ext_vector_type(4))) float f32x4;
typedef __attribute__((ext_vector_type(8))) __bf16 bf16x8;

__device__ __forceinline__ unsigned short f2bf(float f) {
    unsigned int u = __float_as_uint(f);
    u = (u + 0x7FFF + ((u >> 16) & 1)) >> 16;   // RNE
    return (unsigned short)u;
}
__device__ __forceinline__ unsigned int packbf(float a, float b) {
    return (unsigned int)f2bf(a) | ((unsigned int)f2bf(b) << 16);
}
__device__ __forceinline__ float bfu_lo(unsigned int v) {   // low ushort -> float
    return __uint_as_float(v << 16);
}
__device__ __forceinline__ float bfu_hi(unsigned int v) {   // high ushort -> float
    return __uint_as_float(v & 0xFFFF0000u);
}
// async global->LDS DMA, 16 B/lane; LDS dest is wave-uniform base + lane*16
__device__ __forceinline__ void gload_lds16(const void* g, void* l) {
    __builtin_amdgcn_global_load_lds(
        (const __attribute__((address_space(1))) unsigned int*)g,
        (__attribute__((address_space(3))) unsigned int*)l, 16, 0, 0);
}

// W1t[n][k] = bf16(W1[k][n]), k zero-padded to 512; also zeroes bcnt (merged launch)
__global__ void k_prep_w1t(const float* __restrict__ w1, unsigned short* __restrict__ w1t,
                           int* __restrict__ bcnt) {
    int idx = blockIdx.x * blockDim.x + threadIdx.x;
    if (idx < NB) bcnt[idx] = 0;
    if (idx >= HIDDEN * KPAD) return;
    int n = idx >> 9, k = idx & (KPAD - 1);
    float v = (k < F_IN) ? w1[k * HIDDEN + n] : 0.f;
    w1t[idx] = f2bf(v);
}

// ---------- CSR build: bucketed counting sort ----------
__launch_bounds__(1024)
__global__ void k_bhist(const int* __restrict__ dst, int* __restrict__ bcnt, int e) {
    __shared__ int h[NB];
    for (int i = threadIdx.x; i < NB; i += 1024) h[i] = 0;
    __syncthreads();
    int base = blockIdx.x * EPB;
#pragma unroll
    for (int j = 0; j < 16; ++j) {
        int i = base + j * 1024 + threadIdx.x;
        if (i < e) atomicAdd(&h[dst[i] / NPB], 1);
    }
    __syncthreads();
    for (int i = threadIdx.x; i < NB; i += 1024)
        if (h[i]) atomicAdd(&bcnt[i], h[i]);
}

__launch_bounds__(1024)
__global__ void k_bscan(const int* __restrict__ bcnt, int* __restrict__ bptr,
                        int* __restrict__ bcur) {
    __shared__ int s[1024];
    int t = threadIdx.x;
    int a = bcnt[2 * t], b = bcnt[2 * t + 1];
    int v = a + b;
    s[t] = v;
    __syncthreads();
    for (int off = 1; off < 1024; off <<= 1) {
        int u = (t >= off) ? s[t - off] : 0;
        __syncthreads();
        s[t] += u;
        __syncthreads();
    }
    int excl = s[t] - v;
    bptr[2 * t] = excl;     bptr[2 * t + 1] = excl + a;
    bcur[2 * t] = excl;     bcur[2 * t + 1] = excl + a;
    if (t == 1023) bptr[NB] = s[1023];
}

__launch_bounds__(1024)
__global__ void k_bfill(const int* __restrict__ src, const int* __restrict__ dst,
                        int* __restrict__ bcur, int2* __restrict__ ebuf, int e) {
    __shared__ int hist[NB];
    __shared__ int base_[NB];
    for (int i = threadIdx.x; i < NB; i += 1024) hist[i] = 0;
    __syncthreads();
    int b0 = blockIdx.x * EPB;
    int s_[16], d_[16];
#pragma unroll
    for (int j = 0; j < 16; ++j) {
        int i = b0 + j * 1024 + threadIdx.x;
        if (i < e) {
            s_[j] = src[i];
            d_[j] = dst[i];
            atomicAdd(&hist[d_[j] / NPB], 1);
        } else d_[j] = -1;
    }
    __syncthreads();
    for (int i = threadIdx.x; i < NB; i += 1024) {
        int hc = hist[i];
        base_[i] = hc ? atomicAdd(&bcur[i], hc) : 0;
        hist[i] = 0;    // reuse as local cursor
    }
    __syncthreads();
#pragma unroll
    for (int j = 0; j < 16; ++j) {
        if (d_[j] >= 0) {
            int bu = d_[j] / NPB;
            int r = atomicAdd(&hist[bu], 1);
            ebuf[base_[bu] + r] = make_int2(s_[j], d_[j]);
        }
    }
}

__launch_bounds__(256)
__global__ void k_bucket_csr(const int2* __restrict__ ebuf, const int* __restrict__ bptr,
                             int* __restrict__ rp, int* __restrict__ col,
                             float* __restrict__ dinv, int n) {
    int b  = blockIdx.x;
    int lo = b * NPB;
    if (lo >= n) return;
    int hi  = min(lo + NPB, n);
    int eb0 = bptr[b], ec = bptr[b + 1] - eb0;

    __shared__ int2 pairs[CAP];
    __shared__ int  hist[NPB];
    __shared__ int  excl[NPB + 1];
    for (int j = threadIdx.x; j < NPB; j += 256) hist[j] = 0;
    __syncthreads();
    for (int i = threadIdx.x; i < ec; i += 256) {
        int2 p = ebuf[eb0 + i];
        if (i < CAP) pairs[i] = p;
        atomicAdd(&hist[p.y - lo], 1);
    }
    __syncthreads();
    if (threadIdx.x == 0) {
        int acc = 0;
        for (int j = 0; j < NPB; ++j) { excl[j] = acc; acc += hist[j]; }
        excl[NPB] = acc;
    }
    __syncthreads();
    for (int j = threadIdx.x; j < hi - lo; j += 256) {
        rp[lo + j]   = eb0 + excl[j];
        dinv[lo + j] = rsqrtf((float)(hist[j] + 1));   // +1 self loop
    }
    if (hi == n && threadIdx.x == 0) rp[n] = eb0 + ec;
    __syncthreads();
    for (int j = threadIdx.x; j < NPB; j += 256) hist[j] = 0;  // reuse as cursor
    __syncthreads();
    for (int i = threadIdx.x; i < ec; i += 256) {
        int2 p  = (i < CAP) ? pairs[i] : ebuf[eb0 + i];
        int  li = p.y - lo;
        int  r  = atomicAdd(&hist[li], 1);
        col[eb0 + excl[li] + r] = p.x;
    }
}

// ---------- GEMM1: hs[N,64](bf16, pre-scaled by dinv) = dinv * (x @ W1) ----------
// v6: x staged via global_load_lds DMA (no dest VGPR -> compiler cannot sink
// it; 1 KB in flight per instruction). Per-wave triple-buffered 16-row tile,
// prefetch distance 2, counted vmcnt waits. XOR swizzle (row&7)<<4 applied as
// pre-swizzled SOURCE chunk + swizzled ds_read (linear DMA dest). W1^T stays
// LDS-resident (lgkmcnt path). ks=15 column tail peeled to register loads.
__launch_bounds__(512)
__global__ void k_gemm1(const float* __restrict__ x, const unsigned short* __restrict__ w1t,
                        const float* __restrict__ dinv, unsigned short* __restrict__ hs, int n) {
    constexpr int LDW = 520;                       // 512 + 8 ushorts (16B pad)
    __shared__ __align__(16) unsigned short w1l[HIDDEN * LDW];   // 66,560 B
    __shared__ __align__(16) char xs[3][8][2048];                // 49,152 B

    const int tid  = threadIdx.x;
    const int wave = tid >> 6;
    const int lane = tid & 63;
    const int quad = lane >> 4;
    const int l16  = lane & 15;

    // stage W1^T into LDS (once): 4096 16B-chunks, coalesced
    {
        const uint4* g = (const uint4*)w1t;
#pragma unroll
        for (int i = 0; i < 8; ++i) {
            int c   = i * 512 + tid;
            int row = c >> 6, cc = c & 63;
            uint4 v = g[c];
            *(uint4*)&w1l[row * LDW + cc * 8] = v;
        }
    }

    const int rowb = blockIdx.x * 128 + wave * 16;

    // DMA source geometry: lane l stages row (l>>3) of its 8-row half-tile,
    // dest chunk (l&7); source chunk pre-swizzled so a swizzled read returns
    // linear data: LDS[row][c] = x[row][c ^ (row&7)].
    const int rloc = lane >> 3;
    const int csrc = (lane & 7) ^ rloc;
    int gr0 = rowb + rloc;      if (gr0 > n - 1) gr0 = n - 1;
    int gr1 = rowb + 8 + rloc;  if (gr1 > n - 1) gr1 = n - 1;
    const char* sb0 = (const char*)x + (size_t)gr0 * (F_IN * 4) + csrc * 16;
    const char* sb1 = (const char*)x + (size_t)gr1 * (F_IN * 4) + csrc * 16;

    auto STAGE = [&](int ks) {                      // slice ks -> buffer ks%3
        char* d = &xs[ks % 3][wave][0];
        gload_lds16(sb0 + ks * 128, d);
        gload_lds16(sb1 + ks * 128, d + 1024);
    };

    STAGE(0); STAGE(1);
    asm volatile("s_waitcnt vmcnt(0)" ::: "memory");
    __syncthreads();                                // W1 + slices 0,1 visible

    f32x4 acc[4];
#pragma unroll
    for (int ct = 0; ct < 4; ++ct) acc[ct] = (f32x4)0.f;

    const int rb  = l16 * 128;
    const int swz = (l16 & 7) << 4;
    const int o1  = rb + ((quad * 32) ^ swz);
    const int o2  = rb + ((quad * 32 + 16) ^ swz);

#pragma unroll
    for (int ks = 0; ks < 15; ++ks) {
        if (ks + 2 <= 14) STAGE(ks + 2);            // keep 2 slices (4 DMAs) in flight
        if (ks < 13)       asm volatile("s_waitcnt vmcnt(4)" ::: "memory");
        else if (ks == 13) asm volatile("s_waitcnt vmcnt(2)" ::: "memory");
        else               asm volatile("s_waitcnt vmcnt(0)" ::: "memory");

        bf16x8 bfrag[4];
#pragma unroll
        for (int ct = 0; ct < 4; ++ct)
            bfrag[ct] = *(const bf16x8*)&w1l[(ct * 16 + l16) * LDW + ks * 32 + quad * 8];

        const char* xb = &xs[ks % 3][wave][0];
        float4 a0 = *(const float4*)(xb + o1);
        float4 a1 = *(const float4*)(xb + o2);

        union { bf16x8 v; unsigned int u[4]; } af;
        af.u[0] = packbf(a0.x, a0.y); af.u[1] = packbf(a0.z, a0.w);
        af.u[2] = packbf(a1.x, a1.y); af.u[3] = packbf(a1.z, a1.w);
#pragma unroll
        for (int ct = 0; ct < 4; ++ct)
            acc[ct] = __builtin_amdgcn_mfma_f32_16x16x32_bf16(af.v, bfrag[ct], acc[ct], 0, 0, 0);
    }

    {   // peeled ks = 15: columns 480..511, predicated register loads (F_IN=500)
        const int  row = rowb + l16;
        const bool vr  = row < n;
        const float* p = &x[(size_t)(vr ? row : 0) * F_IN];
        const float4 z4 = make_float4(0.f, 0.f, 0.f, 0.f);
        const int c0 = 480 + quad * 8;
        const bool cv0 = (c0 + 4 <= F_IN);          // false only for quad 3
        const bool cv1 = (c0 + 8 <= F_IN);          // false for quads 2,3
        float4 t0 = (vr && cv0) ? *(const float4*)&p[c0]     : z4;
        float4 t1 = (vr && cv1) ? *(const float4*)&p[c0 + 4] : z4;

        bf16x8 bfrag[4];
#pragma unroll
        for (int ct = 0; ct < 4; ++ct)
            bfrag[ct] = *(const bf16x8*)&w1l[(ct * 16 + l16) * LDW + 480 + quad * 8];

        union { bf16x8 v; unsigned int u[4]; } af;
        af.u[0] = packbf(t0.x, t0.y); af.u[1] = packbf(t0.z, t0.w);
        af.u[2] = packbf(t1.x, t1.y); af.u[3] = packbf(t1.z, t1.w);
#pragma unroll
        for (int ct = 0; ct < 4; ++ct)
            acc[ct] = __builtin_amdgcn_mfma_f32_16x16x32_bf16(af.v, bfrag[ct], acc[ct], 0, 0, 0);
    }

    // D layout: row = quad*4 + reg, col = lane&15 ; store bf16 * dinv[row]
#pragma unroll
    for (int reg = 0; reg < 4; ++reg) {
        int grow = rowb + quad * 4 + reg;
        if (grow < n) {
            float dv = dinv[grow];
#pragma unroll
            for (int ct = 0; ct < 4; ++ct)
                hs[(size_t)grow * HIDDEN + ct * 16 + l16] = f2bf(dv * acc[ct][reg]);
        }
    }
}

// ---------- aggregation over pre-scaled bf16 table ----------
// out[i] = dinv[i] * (sum_e hs[col[e]] + hs[i]) + b  (+ReLU or +log_softmax)
// 4 edge streams per wave (16-lane quarters), uint2 (4 bf16 feats) per lane.
// Main loop keeps 16 gathers in flight; fixed 2-step epilogue bounds the
// dependent-chain depth for the remainder (<=3 edges per stream).
template <int F, bool RELU, bool LSM>
__launch_bounds__(256)
__global__ void k_agg(const uint2* __restrict__ hs2, const int* __restrict__ rp,
                      const int* __restrict__ col, const float* __restrict__ dinv,
                      const float* __restrict__ bias, float* __restrict__ out, int n) {
    constexpr int PW2 = F / 4;     // uint2 per row (16 or 10)
    const int lane = threadIdx.x & 63;
    const int q    = lane >> 4;    // edge-stream id 0..3
    const int p    = lane & 15;    // feature-slot within stream
    const bool act = p < PW2;
    int wid = __builtin_amdgcn_readfirstlane((blockIdx.x * blockDim.x + threadIdx.x) >> 6);
    const int nw = (gridDim.x * blockDim.x) >> 6;

    for (; wid < n; wid += nw) {
        const int beg = rp[wid], end = rp[wid + 1];
        float a0 = 0.f, a1 = 0.f, a2 = 0.f, a3 = 0.f;
        int e = beg + q;
        for (; e + 12 < end; e += 16) {          // 16 edges/wave-iter, 16 gathers in flight
            int c0 = col[e], c1 = col[e + 4], c2 = col[e + 8], c3 = col[e + 12];
            uint2 v0 = act ? hs2[(unsigned)c0 * PW2 + p] : make_uint2(0u, 0u);
            uint2 v1 = act ? hs2[(unsigned)c1 * PW2 + p] : make_uint2(0u, 0u);
            uint2 v2 = act ? hs2[(unsigned)c2 * PW2 + p] : make_uint2(0u, 0u);
            uint2 v3 = act ? hs2[(unsigned)c3 * PW2 + p] : make_uint2(0u, 0u);
            a0 += bfu_lo(v0.x) + bfu_lo(v1.x) + bfu_lo(v2.x) + bfu_lo(v3.x);
            a1 += bfu_hi(v0.x) + bfu_hi(v1.x) + bfu_hi(v2.x) + bfu_hi(v3.x);
            a2 += bfu_lo(v0.y) + bfu_lo(v1.y) + bfu_lo(v2.y) + bfu_lo(v3.y);
            a3 += bfu_hi(v0.y) + bfu_hi(v1.y) + bfu_hi(v2.y) + bfu_hi(v3.y);
        }
        if (e + 4 < end) {                       // >=2 edges left in this stream
            int c0 = col[e], c1 = col[e + 4];
            uint2 v0 = act ? hs2[(unsigned)c0 * PW2 + p] : make_uint2(0u, 0u);
            uint2 v1 = act ? hs2[(unsigned)c1 * PW2 + p] : make_uint2(0u, 0u);
            a0 += bfu_lo(v0.x) + bfu_lo(v1.x);
            a1 += bfu_hi(v0.x) + bfu_hi(v1.x);
            a2 += bfu_lo(v0.y) + bfu_lo(v1.y);
            a3 += bfu_hi(v0.y) + bfu_hi(v1.y);
            e += 8;
        }
        if (e < end) {                           // last remaining edge
            int c0 = col[e];
            uint2 v0 = act ? hs2[(unsigned)c0 * PW2 + p] : make_uint2(0u, 0u);
            a0 += bfu_lo(v0.x); a1 += bfu_hi(v0.x);
            a2 += bfu_lo(v0.y); a3 += bfu_hi(v0.y);
        }
        // combine the 4 stream partials
        a0 += __shfl_xor(a0, 16); a1 += __shfl_xor(a1, 16);
        a2 += __shfl_xor(a2, 16); a3 += __shfl_xor(a3, 16);
        a0 += __shfl_xor(a0, 32); a1 += __shfl_xor(a1, 32);
        a2 += __shfl_xor(a2, 32); a3 += __shfl_xor(a3, 32);

        const float di = dinv[wid];
        uint2 sv  = act ? hs2[(unsigned)wid * PW2 + p] : make_uint2(0u, 0u);
        float4 bv = act ? *(const float4*)&bias[4 * p] : make_float4(0.f, 0.f, 0.f, 0.f);
        float r0 = di * (a0 + bfu_lo(sv.x)) + bv.x;
        float r1 = di * (a1 + bfu_hi(sv.x)) + bv.y;
        float r2 = di * (a2 + bfu_lo(sv.y)) + bv.z;
        float r3 = di * (a3 + bfu_hi(sv.y)) + bv.w;
        if (RELU) {
            r0 = fmaxf(r0, 0.f); r1 = fmaxf(r1, 0.f);
            r2 = fmaxf(r2, 0.f); r3 = fmaxf(r3, 0.f);
        }
        if (LSM) {
            float m = act ? fmaxf(fmaxf(r0, r1), fmaxf(r2, r3)) : -INFINITY;
#pragma unroll
            for (int off = 8; off; off >>= 1) m = fmaxf(m, __shfl_xor(m, off));
            float ex = act ? (__expf(r0 - m) + __expf(r1 - m) + __expf(r2 - m) + __expf(r3 - m))
                           : 0.f;
#pragma unroll
            for (int off = 8; off; off >>= 1) ex += __shfl_xor(ex, off);
            float lse = m + __logf(ex);
            r0 -= lse; r1 -= lse; r2 -= lse; r3 -= lse;
        }
        if (q == 0 && act)
            *(float4*)&out[(size_t)wid * F + 4 * p] = make_float4(r0, r1, r2, r3);
    }
}

// ---------- GEMM2: h2s[N,40](bf16, pre-scaled) = dinv * (a[N,64] @ W2[64,40]) ----------
__launch_bounds__(256)
__global__ void k_gemm2(const float* __restrict__ a, const float* __restrict__ w,
                        const float* __restrict__ dinv, unsigned short* __restrict__ out, int n) {
    __shared__ float ws[HIDDEN * N_CLASS];
    for (int idx = threadIdx.x; idx < HIDDEN * N_CLASS; idx += 256) ws[idx] = w[idx];
    __syncthreads();
    int idx = blockIdx.x * 256 + threadIdx.x;
    if (idx >= n * N_CLASS) return;
    int i = idx / N_CLASS, j = idx - i * N_CLASS;
    float s = 0.f;
#pragma unroll
    for (int k = 0; k < HIDDEN; k += 4) {
        float4 xv = *(const float4*)&a[(size_t)i * HIDDEN + k];
        s = fmaf(xv.x, ws[k * N_CLASS + j], s);
        s = fmaf(xv.y, ws[(k + 1) * N_CLASS + j], s);
        s = fmaf(xv.z, ws[(k + 2) * N_CLASS + j], s);
        s = fmaf(xv.w, ws[(k + 3) * N_CLASS + j], s);
    }
    out[idx] = f2bf(dinv[i] * s);
}

extern "C" void kernel_launch(void* const* d_in, const int* in_sizes, int n_in,
                              void* d_out, int out_size, void* d_ws, size_t ws_size,
                              hipStream_t stream) {
    const float* x   = (const float*)d_in[0];
    const float* W1  = (const float*)d_in[1];
    const float* b1  = (const float*)d_in[2];
    const float* W2  = (const float*)d_in[3];
    const float* b2  = (const float*)d_in[4];
    const int*   ei  = (const int*)d_in[5];
    const int*   src = ei;
    const int*   dst = ei + N_EDGES;
    float*       out = (float*)d_out;

    char*  ws  = (char*)d_ws;
    size_t off = 0;
    auto alloc = [&](size_t bytes) -> void* {
        void* p = ws + off;
        off += (bytes + 255) & ~(size_t)255;
        return p;
    };
    int*            bcnt = (int*)alloc((size_t)NB * 4);
    int*            bptr = (int*)alloc((size_t)(NB + 1) * 4);
    int*            bcur = (int*)alloc((size_t)NB * 4);
    int*            rp   = (int*)alloc((size_t)(N_NODES + 1) * 4);
    int*            col  = (int*)alloc((size_t)N_EDGES * 4);
    float*          dinv = (float*)alloc((size_t)N_NODES * 4);
    unsigned short* w1t  = (unsigned short*)alloc((size_t)HIDDEN * KPAD * 2);
    unsigned short* h1s  = (unsigned short*)alloc((size_t)N_NODES * HIDDEN * 2);  // bf16, pre-scaled
    float*          h1a  = (float*)alloc((size_t)N_NODES * HIDDEN * 4);           // fp32
    int2*           ebuf = (int2*)h1a;            // alias: ebuf dead before agg1 writes h1a
    unsigned short* h2s  = h1s;                   // bf16, aliases h1s (dead after agg1)

    const int NBH = (N_EDGES + EPB - 1) / EPB;   // 98

    // CSR build (bucketed counting sort) + W1^T prep (also zeroes bcnt)
    k_prep_w1t<<<(HIDDEN * KPAD + 255) / 256, 256, 0, stream>>>(W1, w1t, bcnt);
    k_bhist<<<NBH, 1024, 0, stream>>>(dst, bcnt, N_EDGES);
    k_bscan<<<1, 1024, 0, stream>>>(bcnt, bptr, bcur);
    k_bfill<<<NBH, 1024, 0, stream>>>(src, dst, bcur, ebuf, N_EDGES);
    k_bucket_csr<<<NB, 256, 0, stream>>>(ebuf, bptr, rp, col, dinv, N_NODES);

    // layer 1
    k_gemm1<<<(N_NODES + 127) / 128, 512, 0, stream>>>(x, w1t, dinv, h1s, N_NODES);
    k_agg<HIDDEN, true, false><<<2048, 256, 0, stream>>>(
        (const uint2*)h1s, rp, col, dinv, b1, h1a, N_NODES);

    // layer 2 (+fused log_softmax)
    k_gemm2<<<(N_NODES * N_CLASS + 255) / 256, 256, 0, stream>>>(h1a, W2, dinv, h2s, N_NODES);
    k_agg<N_CLASS, false, true><<<2048, 256, 0, stream>>>(
        (const uint2*)h2s, rp, col, dinv, b2, out, N_NODES);
}

// Round 8
// 486.917 us; speedup vs baseline: 1.1190x; 1.0001x over previous
//
#include <hip/hip_runtime.h>
#include <math.h>

#define N_NODES 100000
#define N_EDGES 1600000
#define F_IN    500
#define HIDDEN  64
#define N_CLASS 40
#define KPAD    512

#define NB   2048      // dst buckets
#define NPB  49        // nodes per bucket (2048*49 = 100352 >= N)
#define EPB  16384     // edges per block in bhist/bfill
#define CAP  1536      // LDS pair capacity in k_bucket_csr

typedef __attribute__((ext_vector_type(4))) float f32x4;
typedef __attribute__((ext_vector_type(8))) __bf16 bf16x8;

__device__ __forceinline__ unsigned short f2bf(float f) {
    unsigned int u = __float_as_uint(f);
    u = (u + 0x7FFF + ((u >> 16) & 1)) >> 16;   // RNE
    return (unsigned short)u;
}
__device__ __forceinline__ unsigned int packbf(float a, float b) {
    return (unsigned int)f2bf(a) | ((unsigned int)f2bf(b) << 16);
}
__device__ __forceinline__ float bfu_lo(unsigned int v) {   // low ushort -> float
    return __uint_as_float(v << 16);
}
__device__ __forceinline__ float bfu_hi(unsigned int v) {   // high ushort -> float
    return __uint_as_float(v & 0xFFFF0000u);
}
// async global->LDS DMA, 16 B/lane; LDS dest is wave-uniform base + lane*16
__device__ __forceinline__ void gload_lds16(const void* g, void* l) {
    __builtin_amdgcn_global_load_lds(
        (const __attribute__((address_space(1))) unsigned int*)g,
        (__attribute__((address_space(3))) unsigned int*)l, 16, 0, 0);
}

// W1t[n][k] = bf16(W1[k][n]), k zero-padded to 512; also zeroes bcnt (merged launch)
__global__ void k_prep_w1t(const float* __restrict__ w1, unsigned short* __restrict__ w1t,
                           int* __restrict__ bcnt) {
    int idx = blockIdx.x * blockDim.x + threadIdx.x;
    if (idx < NB) bcnt[idx] = 0;
    if (idx >= HIDDEN * KPAD) return;
    int n = idx >> 9, k = idx & (KPAD - 1);
    float v = (k < F_IN) ? w1[k * HIDDEN + n] : 0.f;
    w1t[idx] = f2bf(v);
}

// ---------- CSR build: bucketed counting sort ----------
__launch_bounds__(1024)
__global__ void k_bhist(const int* __restrict__ dst, int* __restrict__ bcnt, int e) {
    __shared__ int h[NB];
    for (int i = threadIdx.x; i < NB; i += 1024) h[i] = 0;
    __syncthreads();
    int base = blockIdx.x * EPB;
#pragma unroll
    for (int j = 0; j < 16; ++j) {
        int i = base + j * 1024 + threadIdx.x;
        if (i < e) atomicAdd(&h[dst[i] / NPB], 1);
    }
    __syncthreads();
    for (int i = threadIdx.x; i < NB; i += 1024)
        if (h[i]) atomicAdd(&bcnt[i], h[i]);
}

__launch_bounds__(1024)
__global__ void k_bscan(const int* __restrict__ bcnt, int* __restrict__ bptr,
                        int* __restrict__ bcur) {
    __shared__ int s[1024];
    int t = threadIdx.x;
    int a = bcnt[2 * t], b = bcnt[2 * t + 1];
    int v = a + b;
    s[t] = v;
    __syncthreads();
    for (int off = 1; off < 1024; off <<= 1) {
        int u = (t >= off) ? s[t - off] : 0;
        __syncthreads();
        s[t] += u;
        __syncthreads();
    }
    int excl = s[t] - v;
    bptr[2 * t] = excl;     bptr[2 * t + 1] = excl + a;
    bcur[2 * t] = excl;     bcur[2 * t + 1] = excl + a;
    if (t == 1023) bptr[NB] = s[1023];
}

__launch_bounds__(1024)
__global__ void k_bfill(const int* __restrict__ src, const int* __restrict__ dst,
                        int* __restrict__ bcur, int2* __restrict__ ebuf, int e) {
    __shared__ int hist[NB];
    __shared__ int base_[NB];
    for (int i = threadIdx.x; i < NB; i += 1024) hist[i] = 0;
    __syncthreads();
    int b0 = blockIdx.x * EPB;
    int s_[16], d_[16];
#pragma unroll
    for (int j = 0; j < 16; ++j) {
        int i = b0 + j * 1024 + threadIdx.x;
        if (i < e) {
            s_[j] = src[i];
            d_[j] = dst[i];
            atomicAdd(&hist[d_[j] / NPB], 1);
        } else d_[j] = -1;
    }
    __syncthreads();
    for (int i = threadIdx.x; i < NB; i += 1024) {
        int hc = hist[i];
        base_[i] = hc ? atomicAdd(&bcur[i], hc) : 0;
        hist[i] = 0;    // reuse as local cursor
    }
    __syncthreads();
#pragma unroll
    for (int j = 0; j < 16; ++j) {
        if (d_[j] >= 0) {
            int bu = d_[j] / NPB;
            int r = atomicAdd(&hist[bu], 1);
            ebuf[base_[bu] + r] = make_int2(s_[j], d_[j]);
        }
    }
}

__launch_bounds__(256)
__global__ void k_bucket_csr(const int2* __restrict__ ebuf, const int* __restrict__ bptr,
                             int* __restrict__ rp, int* __restrict__ col,
                             float* __restrict__ dinv, int n) {
    int b  = blockIdx.x;
    int lo = b * NPB;
    if (lo >= n) return;
    int hi  = min(lo + NPB, n);
    int eb0 = bptr[b], ec = bptr[b + 1] - eb0;

    __shared__ int2 pairs[CAP];
    __shared__ int  hist[NPB];
    __shared__ int  excl[NPB + 1];
    for (int j = threadIdx.x; j < NPB; j += 256) hist[j] = 0;
    __syncthreads();
    for (int i = threadIdx.x; i < ec; i += 256) {
        int2 p = ebuf[eb0 + i];
        if (i < CAP) pairs[i] = p;
        atomicAdd(&hist[p.y - lo], 1);
    }
    __syncthreads();
    if (threadIdx.x == 0) {
        int acc = 0;
        for (int j = 0; j < NPB; ++j) { excl[j] = acc; acc += hist[j]; }
        excl[NPB] = acc;
    }
    __syncthreads();
    for (int j = threadIdx.x; j < hi - lo; j += 256) {
        rp[lo + j]   = eb0 + excl[j];
        dinv[lo + j] = rsqrtf((float)(hist[j] + 1));   // +1 self loop
    }
    if (hi == n && threadIdx.x == 0) rp[n] = eb0 + ec;
    __syncthreads();
    for (int j = threadIdx.x; j < NPB; j += 256) hist[j] = 0;  // reuse as cursor
    __syncthreads();
    for (int i = threadIdx.x; i < ec; i += 256) {
        int2 p  = (i < CAP) ? pairs[i] : ebuf[eb0 + i];
        int  li = p.y - lo;
        int  r  = atomicAdd(&hist[li], 1);
        col[eb0 + excl[li] + r] = p.x;
    }
}

// ---------- GEMM1: hs[N,64](bf16, pre-scaled by dinv) = dinv * (x @ W1) ----------
// v7: same DMA structure as v6, but prefetch distance 4 (5 LDS buffers):
// steady-state wait is vmcnt(8) with 4 compute iterations (~1000 cy) covering
// the ~900 cy HBM latency. Barrier moved BEFORE the x-STAGEs so the compiler's
// full drain at s_barrier doesn't flush the prologue prefetch.
__launch_bounds__(512)
__global__ void k_gemm1(const float* __restrict__ x, const unsigned short* __restrict__ w1t,
                        const float* __restrict__ dinv, unsigned short* __restrict__ hs, int n) {
    constexpr int LDW = 520;                       // 512 + 8 ushorts (16B pad)
    __shared__ __align__(16) unsigned short w1l[HIDDEN * LDW];   // 66,560 B
    __shared__ __align__(16) char xs[5][8][2048];                // 81,920 B

    const int tid  = threadIdx.x;
    const int wave = tid >> 6;
    const int lane = tid & 63;
    const int quad = lane >> 4;
    const int l16  = lane & 15;

    // stage W1^T into LDS (once): 4096 16B-chunks, coalesced
    {
        const uint4* g = (const uint4*)w1t;
#pragma unroll
        for (int i = 0; i < 8; ++i) {
            int c   = i * 512 + tid;
            int row = c >> 6, cc = c & 63;
            uint4 v = g[c];
            *(uint4*)&w1l[row * LDW + cc * 8] = v;
        }
    }
    __syncthreads();                                // w1l visible; drains prologue loads only

    const int rowb = blockIdx.x * 128 + wave * 16;

    // DMA source geometry: lane l stages row (l>>3) of its 8-row half-tile,
    // dest chunk (l&7); source chunk pre-swizzled so a swizzled read returns
    // linear data: LDS[row][c] = x[row][c ^ (row&7)].
    const int rloc = lane >> 3;
    const int csrc = (lane & 7) ^ rloc;
    int gr0 = rowb + rloc;      if (gr0 > n - 1) gr0 = n - 1;
    int gr1 = rowb + 8 + rloc;  if (gr1 > n - 1) gr1 = n - 1;
    const char* sb0 = (const char*)x + (size_t)gr0 * (F_IN * 4) + csrc * 16;
    const char* sb1 = (const char*)x + (size_t)gr1 * (F_IN * 4) + csrc * 16;

    auto STAGE = [&](int ks) {                      // slice ks -> buffer ks%5
        char* d = &xs[ks % 5][wave][0];
        gload_lds16(sb0 + ks * 128, d);
        gload_lds16(sb1 + ks * 128, d + 1024);
    };

    STAGE(0); STAGE(1); STAGE(2); STAGE(3);         // 8 DMAs in flight

    f32x4 acc[4];
#pragma unroll
    for (int ct = 0; ct < 4; ++ct) acc[ct] = (f32x4)0.f;

    const int rb  = l16 * 128;
    const int swz = (l16 & 7) << 4;
    const int o1  = rb + ((quad * 32) ^ swz);
    const int o2  = rb + ((quad * 32 + 16) ^ swz);

#pragma unroll
    for (int ks = 0; ks < 15; ++ks) {
        if (ks + 4 <= 14) STAGE(ks + 4);            // keep 4 slices (8 DMAs) in flight
        if (ks <= 10)      asm volatile("s_waitcnt vmcnt(8)" ::: "memory");
        else if (ks == 11) asm volatile("s_waitcnt vmcnt(6)" ::: "memory");
        else if (ks == 12) asm volatile("s_waitcnt vmcnt(4)" ::: "memory");
        else if (ks == 13) asm volatile("s_waitcnt vmcnt(2)" ::: "memory");
        else               asm volatile("s_waitcnt vmcnt(0)" ::: "memory");

        bf16x8 bfrag[4];
#pragma unroll
        for (int ct = 0; ct < 4; ++ct)
            bfrag[ct] = *(const bf16x8*)&w1l[(ct * 16 + l16) * LDW + ks * 32 + quad * 8];

        const char* xb = &xs[ks % 5][wave][0];
        float4 a0 = *(const float4*)(xb + o1);
        float4 a1 = *(const float4*)(xb + o2);

        union { bf16x8 v; unsigned int u[4]; } af;
        af.u[0] = packbf(a0.x, a0.y); af.u[1] = packbf(a0.z, a0.w);
        af.u[2] = packbf(a1.x, a1.y); af.u[3] = packbf(a1.z, a1.w);
#pragma unroll
        for (int ct = 0; ct < 4; ++ct)
            acc[ct] = __builtin_amdgcn_mfma_f32_16x16x32_bf16(af.v, bfrag[ct], acc[ct], 0, 0, 0);
    }

    {   // peeled ks = 15: columns 480..511, predicated register loads (F_IN=500)
        const int  row = rowb + l16;
        const bool vr  = row < n;
        const float* p = &x[(size_t)(vr ? row : 0) * F_IN];
        const float4 z4 = make_float4(0.f, 0.f, 0.f, 0.f);
        const int c0 = 480 + quad * 8;
        const bool cv0 = (c0 + 4 <= F_IN);          // false only for quad 3
        const bool cv1 = (c0 + 8 <= F_IN);          // false for quads 2,3
        float4 t0 = (vr && cv0) ? *(const float4*)&p[c0]     : z4;
        float4 t1 = (vr && cv1) ? *(const float4*)&p[c0 + 4] : z4;

        bf16x8 bfrag[4];
#pragma unroll
        for (int ct = 0; ct < 4; ++ct)
            bfrag[ct] = *(const bf16x8*)&w1l[(ct * 16 + l16) * LDW + 480 + quad * 8];

        union { bf16x8 v; unsigned int u[4]; } af;
        af.u[0] = packbf(t0.x, t0.y); af.u[1] = packbf(t0.z, t0.w);
        af.u[2] = packbf(t1.x, t1.y); af.u[3] = packbf(t1.z, t1.w);
#pragma unroll
        for (int ct = 0; ct < 4; ++ct)
            acc[ct] = __builtin_amdgcn_mfma_f32_16x16x32_bf16(af.v, bfrag[ct], acc[ct], 0, 0, 0);
    }

    // D layout: row = quad*4 + reg, col = lane&15 ; store bf16 * dinv[row]
#pragma unroll
    for (int reg = 0; reg < 4; ++reg) {
        int grow = rowb + quad * 4 + reg;
        if (grow < n) {
            float dv = dinv[grow];
#pragma unroll
            for (int ct = 0; ct < 4; ++ct)
                hs[(size_t)grow * HIDDEN + ct * 16 + l16] = f2bf(dv * acc[ct][reg]);
        }
    }
}

// ---------- aggregation over pre-scaled bf16 table ----------
// out[i] = dinv[i] * (sum_e hs[col[e]] + hs[i]) + b  (+ReLU or +log_softmax)
// 4 edge streams per wave (16-lane quarters), uint2 (4 bf16 feats) per lane.
// Main loop keeps 16 gathers in flight; fixed 2-step epilogue bounds the
// dependent-chain depth for the remainder (<=3 edges per stream).
template <int F, bool RELU, bool LSM>
__launch_bounds__(256)
__global__ void k_agg(const uint2* __restrict__ hs2, const int* __restrict__ rp,
                      const int* __restrict__ col, const float* __restrict__ dinv,
                      const float* __restrict__ bias, float* __restrict__ out, int n) {
    constexpr int PW2 = F / 4;     // uint2 per row (16 or 10)
    const int lane = threadIdx.x & 63;
    const int q    = lane >> 4;    // edge-stream id 0..3
    const int p    = lane & 15;    // feature-slot within stream
    const bool act = p < PW2;
    int wid = __builtin_amdgcn_readfirstlane((blockIdx.x * blockDim.x + threadIdx.x) >> 6);
    const int nw = (gridDim.x * blockDim.x) >> 6;

    for (; wid < n; wid += nw) {
        const int beg = rp[wid], end = rp[wid + 1];
        float a0 = 0.f, a1 = 0.f, a2 = 0.f, a3 = 0.f;
        int e = beg + q;
        for (; e + 12 < end; e += 16) {          // 16 edges/wave-iter, 16 gathers in flight
            int c0 = col[e], c1 = col[e + 4], c2 = col[e + 8], c3 = col[e + 12];
            uint2 v0 = act ? hs2[(unsigned)c0 * PW2 + p] : make_uint2(0u, 0u);
            uint2 v1 = act ? hs2[(unsigned)c1 * PW2 + p] : make_uint2(0u, 0u);
            uint2 v2 = act ? hs2[(unsigned)c2 * PW2 + p] : make_uint2(0u, 0u);
            uint2 v3 = act ? hs2[(unsigned)c3 * PW2 + p] : make_uint2(0u, 0u);
            a0 += bfu_lo(v0.x) + bfu_lo(v1.x) + bfu_lo(v2.x) + bfu_lo(v3.x);
            a1 += bfu_hi(v0.x) + bfu_hi(v1.x) + bfu_hi(v2.x) + bfu_hi(v3.x);
            a2 += bfu_lo(v0.y) + bfu_lo(v1.y) + bfu_lo(v2.y) + bfu_lo(v3.y);
            a3 += bfu_hi(v0.y) + bfu_hi(v1.y) + bfu_hi(v2.y) + bfu_hi(v3.y);
        }
        if (e + 4 < end) {                       // >=2 edges left in this stream
            int c0 = col[e], c1 = col[e + 4];
            uint2 v0 = act ? hs2[(unsigned)c0 * PW2 + p] : make_uint2(0u, 0u);
            uint2 v1 = act ? hs2[(unsigned)c1 * PW2 + p] : make_uint2(0u, 0u);
            a0 += bfu_lo(v0.x) + bfu_lo(v1.x);
            a1 += bfu_hi(v0.x) + bfu_hi(v1.x);
            a2 += bfu_lo(v0.y) + bfu_lo(v1.y);
            a3 += bfu_hi(v0.y) + bfu_hi(v1.y);
            e += 8;
        }
        if (e < end) {                           // last remaining edge
            int c0 = col[e];
            uint2 v0 = act ? hs2[(unsigned)c0 * PW2 + p] : make_uint2(0u, 0u);
            a0 += bfu_lo(v0.x); a1 += bfu_hi(v0.x);
            a2 += bfu_lo(v0.y); a3 += bfu_hi(v0.y);
        }
        // combine the 4 stream partials
        a0 += __shfl_xor(a0, 16); a1 += __shfl_xor(a1, 16);
        a2 += __shfl_xor(a2, 16); a3 += __shfl_xor(a3, 16);
        a0 += __shfl_xor(a0, 32); a1 += __shfl_xor(a1, 32);
        a2 += __shfl_xor(a2, 32); a3 += __shfl_xor(a3, 32);

        const float di = dinv[wid];
        uint2 sv  = act ? hs2[(unsigned)wid * PW2 + p] : make_uint2(0u, 0u);
        float4 bv = act ? *(const float4*)&bias[4 * p] : make_float4(0.f, 0.f, 0.f, 0.f);
        float r0 = di * (a0 + bfu_lo(sv.x)) + bv.x;
        float r1 = di * (a1 + bfu_hi(sv.x)) + bv.y;
        float r2 = di * (a2 + bfu_lo(sv.y)) + bv.z;
        float r3 = di * (a3 + bfu_hi(sv.y)) + bv.w;
        if (RELU) {
            r0 = fmaxf(r0, 0.f); r1 = fmaxf(r1, 0.f);
            r2 = fmaxf(r2, 0.f); r3 = fmaxf(r3, 0.f);
        }
        if (LSM) {
            float m = act ? fmaxf(fmaxf(r0, r1), fmaxf(r2, r3)) : -INFINITY;
#pragma unroll
            for (int off = 8; off; off >>= 1) m = fmaxf(m, __shfl_xor(m, off));
            float ex = act ? (__expf(r0 - m) + __expf(r1 - m) + __expf(r2 - m) + __expf(r3 - m))
                           : 0.f;
#pragma unroll
            for (int off = 8; off; off >>= 1) ex += __shfl_xor(ex, off);
            float lse = m + __logf(ex);
            r0 -= lse; r1 -= lse; r2 -= lse; r3 -= lse;
        }
        if (q == 0 && act)
            *(float4*)&out[(size_t)wid * F + 4 * p] = make_float4(r0, r1, r2, r3);
    }
}

// ---------- GEMM2: h2s[N,40](bf16, pre-scaled) = dinv * (a[N,64] @ W2[64,40]) ----------
__launch_bounds__(256)
__global__ void k_gemm2(const float* __restrict__ a, const float* __restrict__ w,
                        const float* __restrict__ dinv, unsigned short* __restrict__ out, int n) {
    __shared__ float ws[HIDDEN * N_CLASS];
    for (int idx = threadIdx.x; idx < HIDDEN * N_CLASS; idx += 256) ws[idx] = w[idx];
    __syncthreads();
    int idx = blockIdx.x * 256 + threadIdx.x;
    if (idx >= n * N_CLASS) return;
    int i = idx / N_CLASS, j = idx - i * N_CLASS;
    float s = 0.f;
#pragma unroll
    for (int k = 0; k < HIDDEN; k += 4) {
        float4 xv = *(const float4*)&a[(size_t)i * HIDDEN + k];
        s = fmaf(xv.x, ws[k * N_CLASS + j], s);
        s = fmaf(xv.y, ws[(k + 1) * N_CLASS + j], s);
        s = fmaf(xv.z, ws[(k + 2) * N_CLASS + j], s);
        s = fmaf(xv.w, ws[(k + 3) * N_CLASS + j], s);
    }
    out[idx] = f2bf(dinv[i] * s);
}

extern "C" void kernel_launch(void* const* d_in, const int* in_sizes, int n_in,
                              void* d_out, int out_size, void* d_ws, size_t ws_size,
                              hipStream_t stream) {
    const float* x   = (const float*)d_in[0];
    const float* W1  = (const float*)d_in[1];
    const float* b1  = (const float*)d_in[2];
    const float* W2  = (const float*)d_in[3];
    const float* b2  = (const float*)d_in[4];
    const int*   ei  = (const int*)d_in[5];
    const int*   src = ei;
    const int*   dst = ei + N_EDGES;
    float*       out = (float*)d_out;

    char*  ws  = (char*)d_ws;
    size_t off = 0;
    auto alloc = [&](size_t bytes) -> void* {
        void* p = ws + off;
        off += (bytes + 255) & ~(size_t)255;
        return p;
    };
    int*            bcnt = (int*)alloc((size_t)NB * 4);
    int*            bptr = (int*)alloc((size_t)(NB + 1) * 4);
    int*            bcur = (int*)alloc((size_t)NB * 4);
    int*            rp   = (int*)alloc((size_t)(N_NODES + 1) * 4);
    int*            col  = (int*)alloc((size_t)N_EDGES * 4);
    float*          dinv = (float*)alloc((size_t)N_NODES * 4);
    unsigned short* w1t  = (unsigned short*)alloc((size_t)HIDDEN * KPAD * 2);
    unsigned short* h1s  = (unsigned short*)alloc((size_t)N_NODES * HIDDEN * 2);  // bf16, pre-scaled
    float*          h1a  = (float*)alloc((size_t)N_NODES * HIDDEN * 4);           // fp32
    int2*           ebuf = (int2*)h1a;            // alias: ebuf dead before agg1 writes h1a
    unsigned short* h2s  = h1s;                   // bf16, aliases h1s (dead after agg1)

    const int NBH = (N_EDGES + EPB - 1) / EPB;   // 98

    // CSR build (bucketed counting sort) + W1^T prep (also zeroes bcnt)
    k_prep_w1t<<<(HIDDEN * KPAD + 255) / 256, 256, 0, stream>>>(W1, w1t, bcnt);
    k_bhist<<<NBH, 1024, 0, stream>>>(dst, bcnt, N_EDGES);
    k_bscan<<<1, 1024, 0, stream>>>(bcnt, bptr, bcur);
    k_bfill<<<NBH, 1024, 0, stream>>>(src, dst, bcur, ebuf, N_EDGES);
    k_bucket_csr<<<NB, 256, 0, stream>>>(ebuf, bptr, rp, col, dinv, N_NODES);

    // layer 1
    k_gemm1<<<(N_NODES + 127) / 128, 512, 0, stream>>>(x, w1t, dinv, h1s, N_NODES);
    k_agg<HIDDEN, true, false><<<2048, 256, 0, stream>>>(
        (const uint2*)h1s, rp, col, dinv, b1, h1a, N_NODES);

    // layer 2 (+fused log_softmax)
    k_gemm2<<<(N_NODES * N_CLASS + 255) / 256, 256, 0, stream>>>(h1a, W2, dinv, h2s, N_NODES);
    k_agg<N_CLASS, false, true><<<2048, 256, 0, stream>>>(
        (const uint2*)h2s, rp, col, dinv, b2, out, N_NODES);
}

// Round 9
// 482.915 us; speedup vs baseline: 1.1283x; 1.0083x over previous
//
#include <hip/hip_runtime.h>
#include <math.h>

#define N_NODES 100000
#define N_EDGES 1600000
#define F_IN    500
#define HIDDEN  64
#define N_CLASS 40
#define KPAD    512

#define NB   2048      // dst buckets
#define NPB  49        // nodes per bucket (2048*49 = 100352 >= N)
#define EPB  16384     // edges per block in bhist/bfill
#define CAP  1536      // LDS pair capacity in k_bucket_csr

typedef __attribute__((ext_vector_type(4))) float f32x4;
typedef __attribute__((ext_vector_type(8))) __bf16 bf16x8;

__device__ __forceinline__ unsigned short f2bf(float f) {
    unsigned int u = __float_as_uint(f);
    u = (u + 0x7FFF + ((u >> 16) & 1)) >> 16;   // RNE
    return (unsigned short)u;
}
__device__ __forceinline__ unsigned int packbf(float a, float b) {
    return (unsigned int)f2bf(a) | ((unsigned int)f2bf(b) << 16);
}
__device__ __forceinline__ float bfu_lo(unsigned int v) {   // low ushort -> float
    return __uint_as_float(v << 16);
}
__device__ __forceinline__ float bfu_hi(unsigned int v) {   // high ushort -> float
    return __uint_as_float(v & 0xFFFF0000u);
}
// async global->LDS DMA, 16 B/lane; LDS dest is wave-uniform base + lane*16
__device__ __forceinline__ void gload_lds16(const void* g, void* l) {
    __builtin_amdgcn_global_load_lds(
        (const __attribute__((address_space(1))) unsigned int*)g,
        (__attribute__((address_space(3))) unsigned int*)l, 16, 0, 0);
}

// W1t[n][k] = bf16(W1[k][n]), k zero-padded to 512; also zeroes bcnt (merged launch)
__global__ void k_prep_w1t(const float* __restrict__ w1, unsigned short* __restrict__ w1t,
                           int* __restrict__ bcnt) {
    int idx = blockIdx.x * blockDim.x + threadIdx.x;
    if (idx < NB) bcnt[idx] = 0;
    if (idx >= HIDDEN * KPAD) return;
    int n = idx >> 9, k = idx & (KPAD - 1);
    float v = (k < F_IN) ? w1[k * HIDDEN + n] : 0.f;
    w1t[idx] = f2bf(v);
}

// ---------- CSR build: bucketed counting sort ----------
__launch_bounds__(1024)
__global__ void k_bhist(const int* __restrict__ dst, int* __restrict__ bcnt, int e) {
    __shared__ int h[NB];
    for (int i = threadIdx.x; i < NB; i += 1024) h[i] = 0;
    __syncthreads();
    int base = blockIdx.x * EPB;
#pragma unroll
    for (int j = 0; j < 16; ++j) {
        int i = base + j * 1024 + threadIdx.x;
        if (i < e) atomicAdd(&h[dst[i] / NPB], 1);
    }
    __syncthreads();
    for (int i = threadIdx.x; i < NB; i += 1024)
        if (h[i]) atomicAdd(&bcnt[i], h[i]);
}

__launch_bounds__(1024)
__global__ void k_bscan(const int* __restrict__ bcnt, int* __restrict__ bptr,
                        int* __restrict__ bcur) {
    __shared__ int s[1024];
    int t = threadIdx.x;
    int a = bcnt[2 * t], b = bcnt[2 * t + 1];
    int v = a + b;
    s[t] = v;
    __syncthreads();
    for (int off = 1; off < 1024; off <<= 1) {
        int u = (t >= off) ? s[t - off] : 0;
        __syncthreads();
        s[t] += u;
        __syncthreads();
    }
    int excl = s[t] - v;
    bptr[2 * t] = excl;     bptr[2 * t + 1] = excl + a;
    bcur[2 * t] = excl;     bcur[2 * t + 1] = excl + a;
    if (t == 1023) bptr[NB] = s[1023];
}

__launch_bounds__(1024)
__global__ void k_bfill(const int* __restrict__ src, const int* __restrict__ dst,
                        int* __restrict__ bcur, int2* __restrict__ ebuf, int e) {
    __shared__ int hist[NB];
    __shared__ int base_[NB];
    for (int i = threadIdx.x; i < NB; i += 1024) hist[i] = 0;
    __syncthreads();
    int b0 = blockIdx.x * EPB;
    int s_[16], d_[16];
#pragma unroll
    for (int j = 0; j < 16; ++j) {
        int i = b0 + j * 1024 + threadIdx.x;
        if (i < e) {
            s_[j] = src[i];
            d_[j] = dst[i];
            atomicAdd(&hist[d_[j] / NPB], 1);
        } else d_[j] = -1;
    }
    __syncthreads();
    for (int i = threadIdx.x; i < NB; i += 1024) {
        int hc = hist[i];
        base_[i] = hc ? atomicAdd(&bcur[i], hc) : 0;
        hist[i] = 0;    // reuse as local cursor
    }
    __syncthreads();
#pragma unroll
    for (int j = 0; j < 16; ++j) {
        if (d_[j] >= 0) {
            int bu = d_[j] / NPB;
            int r = atomicAdd(&hist[bu], 1);
            ebuf[base_[bu] + r] = make_int2(s_[j], d_[j]);
        }
    }
}

__launch_bounds__(256)
__global__ void k_bucket_csr(const int2* __restrict__ ebuf, const int* __restrict__ bptr,
                             int* __restrict__ rp, int* __restrict__ col,
                             float* __restrict__ dinv, int n) {
    int b  = blockIdx.x;
    int lo = b * NPB;
    if (lo >= n) return;
    int hi  = min(lo + NPB, n);
    int eb0 = bptr[b], ec = bptr[b + 1] - eb0;

    __shared__ int2 pairs[CAP];
    __shared__ int  hist[NPB];
    __shared__ int  excl[NPB + 1];
    for (int j = threadIdx.x; j < NPB; j += 256) hist[j] = 0;
    __syncthreads();
    for (int i = threadIdx.x; i < ec; i += 256) {
        int2 p = ebuf[eb0 + i];
        if (i < CAP) pairs[i] = p;
        atomicAdd(&hist[p.y - lo], 1);
    }
    __syncthreads();
    if (threadIdx.x == 0) {
        int acc = 0;
        for (int j = 0; j < NPB; ++j) { excl[j] = acc; acc += hist[j]; }
        excl[NPB] = acc;
    }
    __syncthreads();
    for (int j = threadIdx.x; j < hi - lo; j += 256) {
        rp[lo + j]   = eb0 + excl[j];
        dinv[lo + j] = rsqrtf((float)(hist[j] + 1));   // +1 self loop
    }
    if (hi == n && threadIdx.x == 0) rp[n] = eb0 + ec;
    __syncthreads();
    for (int j = threadIdx.x; j < NPB; j += 256) hist[j] = 0;  // reuse as cursor
    __syncthreads();
    for (int i = threadIdx.x; i < ec; i += 256) {
        int2 p  = (i < CAP) ? pairs[i] : ebuf[eb0 + i];
        int  li = p.y - lo;
        int  r  = atomicAdd(&hist[li], 1);
        col[eb0 + excl[li] + r] = p.x;
    }
}

// ---------- GEMM1: hs[N,64](bf16, pre-scaled by dinv) = dinv * (x @ W1) ----------
// v8: same DMA structure as v7 (depth-4, 5 buffers), but the xs reads are
// inline-asm ds_read_b128 with an EMBEDDED s_waitcnt lgkmcnt(0). This hides
// the LDS-DMA alias from SIInsertWaitcnts, which otherwise inserts a
// conservative vmcnt(0) before every compiler-visible ds_read of a region
// written by global_load_lds -- collapsing the counted-vmcnt pipeline
// (the R7==R8 depth-insensitivity). Outputs are asm results, so consumers
// data-depend on the block (no hoist hazard). Volatile-asm program order vs
// the vmcnt-ladder asms provides DMA->read ordering.
__launch_bounds__(512)
__global__ void k_gemm1(const float* __restrict__ x, const unsigned short* __restrict__ w1t,
                        const float* __restrict__ dinv, unsigned short* __restrict__ hs, int n) {
    constexpr int LDW = 520;                       // 512 + 8 ushorts (16B pad)
    __shared__ __align__(16) unsigned short w1l[HIDDEN * LDW];   // 66,560 B
    __shared__ __align__(16) char xs[5][8][2048];                // 81,920 B

    const int tid  = threadIdx.x;
    const int wave = tid >> 6;
    const int lane = tid & 63;
    const int quad = lane >> 4;
    const int l16  = lane & 15;

    // stage W1^T into LDS (once): 4096 16B-chunks, coalesced
    {
        const uint4* g = (const uint4*)w1t;
#pragma unroll
        for (int i = 0; i < 8; ++i) {
            int c   = i * 512 + tid;
            int row = c >> 6, cc = c & 63;
            uint4 v = g[c];
            *(uint4*)&w1l[row * LDW + cc * 8] = v;
        }
    }
    __syncthreads();                                // w1l visible; drains staging loads only

    const int rowb = blockIdx.x * 128 + wave * 16;

    // DMA source geometry: lane l stages row (l>>3) of its 8-row half-tile,
    // dest chunk (l&7); source chunk pre-swizzled so a swizzled read returns
    // linear data: LDS[row][c] = x[row][c ^ (row&7)].
    const int rloc = lane >> 3;
    const int csrc = (lane & 7) ^ rloc;
    int gr0 = rowb + rloc;      if (gr0 > n - 1) gr0 = n - 1;
    int gr1 = rowb + 8 + rloc;  if (gr1 > n - 1) gr1 = n - 1;
    const char* sb0 = (const char*)x + (size_t)gr0 * (F_IN * 4) + csrc * 16;
    const char* sb1 = (const char*)x + (size_t)gr1 * (F_IN * 4) + csrc * 16;

    auto STAGE = [&](int ks) {                      // slice ks -> buffer ks%5
        char* d = &xs[ks % 5][wave][0];
        gload_lds16(sb0 + ks * 128, d);
        gload_lds16(sb1 + ks * 128, d + 1024);
    };

    STAGE(0); STAGE(1); STAGE(2); STAGE(3);         // 8 DMAs in flight

    f32x4 acc[4];
#pragma unroll
    for (int ct = 0; ct < 4; ++ct) acc[ct] = (f32x4)0.f;

    const int rb  = l16 * 128;
    const int swz = (l16 & 7) << 4;
    const int o1  = rb + ((quad * 32) ^ swz);
    const int o2  = rb + ((quad * 32 + 16) ^ swz);

#pragma unroll
    for (int ks = 0; ks < 15; ++ks) {
        if (ks + 4 <= 14) STAGE(ks + 4);            // keep 4 slices (8 DMAs) in flight
        if (ks <= 10)      asm volatile("s_waitcnt vmcnt(8)" ::: "memory");
        else if (ks == 11) asm volatile("s_waitcnt vmcnt(6)" ::: "memory");
        else if (ks == 12) asm volatile("s_waitcnt vmcnt(4)" ::: "memory");
        else if (ks == 13) asm volatile("s_waitcnt vmcnt(2)" ::: "memory");
        else               asm volatile("s_waitcnt vmcnt(0)" ::: "memory");

        bf16x8 bfrag[4];
#pragma unroll
        for (int ct = 0; ct < 4; ++ct)
            bfrag[ct] = *(const bf16x8*)&w1l[(ct * 16 + l16) * LDW + ks * 32 + quad * 8];

        // xs reads via inline asm: invisible to SIInsertWaitcnts' LDS-DMA
        // alias tracking; embedded lgkmcnt(0) completes them before use.
        const char* xb = &xs[ks % 5][wave][0];
        unsigned alo = (unsigned)(unsigned long long)(xb + o1);
        unsigned ahi = (unsigned)(unsigned long long)(xb + o2);
        f32x4 a0, a1;
        asm volatile("ds_read_b128 %0, %2\n\t"
                     "ds_read_b128 %1, %3\n\t"
                     "s_waitcnt lgkmcnt(0)"
                     : "=&v"(a0), "=&v"(a1)
                     : "v"(alo), "v"(ahi));

        union { bf16x8 v; unsigned int u[4]; } af;
        af.u[0] = packbf(a0[0], a0[1]); af.u[1] = packbf(a0[2], a0[3]);
        af.u[2] = packbf(a1[0], a1[1]); af.u[3] = packbf(a1[2], a1[3]);
#pragma unroll
        for (int ct = 0; ct < 4; ++ct)
            acc[ct] = __builtin_amdgcn_mfma_f32_16x16x32_bf16(af.v, bfrag[ct], acc[ct], 0, 0, 0);
    }

    {   // peeled ks = 15: columns 480..511, predicated register loads (F_IN=500)
        const int  row = rowb + l16;
        const bool vr  = row < n;
        const float* p = &x[(size_t)(vr ? row : 0) * F_IN];
        const float4 z4 = make_float4(0.f, 0.f, 0.f, 0.f);
        const int c0 = 480 + quad * 8;
        const bool cv0 = (c0 + 4 <= F_IN);          // false only for quad 3
        const bool cv1 = (c0 + 8 <= F_IN);          // false for quads 2,3
        float4 t0 = (vr && cv0) ? *(const float4*)&p[c0]     : z4;
        float4 t1 = (vr && cv1) ? *(const float4*)&p[c0 + 4] : z4;

        bf16x8 bfrag[4];
#pragma unroll
        for (int ct = 0; ct < 4; ++ct)
            bfrag[ct] = *(const bf16x8*)&w1l[(ct * 16 + l16) * LDW + 480 + quad * 8];

        union { bf16x8 v; unsigned int u[4]; } af;
        af.u[0] = packbf(t0.x, t0.y); af.u[1] = packbf(t0.z, t0.w);
        af.u[2] = packbf(t1.x, t1.y); af.u[3] = packbf(t1.z, t1.w);
#pragma unroll
        for (int ct = 0; ct < 4; ++ct)
            acc[ct] = __builtin_amdgcn_mfma_f32_16x16x32_bf16(af.v, bfrag[ct], acc[ct], 0, 0, 0);
    }

    // D layout: row = quad*4 + reg, col = lane&15 ; store bf16 * dinv[row]
#pragma unroll
    for (int reg = 0; reg < 4; ++reg) {
        int grow = rowb + quad * 4 + reg;
        if (grow < n) {
            float dv = dinv[grow];
#pragma unroll
            for (int ct = 0; ct < 4; ++ct)
                hs[(size_t)grow * HIDDEN + ct * 16 + l16] = f2bf(dv * acc[ct][reg]);
        }
    }
}

// ---------- aggregation over pre-scaled bf16 table ----------
// out[i] = dinv[i] * (sum_e hs[col[e]] + hs[i]) + b  (+ReLU or +log_softmax)
// 4 edge streams per wave (16-lane quarters), uint2 (4 bf16 feats) per lane.
// Main loop keeps 16 gathers in flight; fixed 2-step epilogue bounds the
// dependent-chain depth for the remainder (<=3 edges per stream).
template <int F, bool RELU, bool LSM>
__launch_bounds__(256)
__global__ void k_agg(const uint2* __restrict__ hs2, const int* __restrict__ rp,
                      const int* __restrict__ col, const float* __restrict__ dinv,
                      const float* __restrict__ bias, float* __restrict__ out, int n) {
    constexpr int PW2 = F / 4;     // uint2 per row (16 or 10)
    const int lane = threadIdx.x & 63;
    const int q    = lane >> 4;    // edge-stream id 0..3
    const int p    = lane & 15;    // feature-slot within stream
    const bool act = p < PW2;
    int wid = __builtin_amdgcn_readfirstlane((blockIdx.x * blockDim.x + threadIdx.x) >> 6);
    const int nw = (gridDim.x * blockDim.x) >> 6;

    for (; wid < n; wid += nw) {
        const int beg = rp[wid], end = rp[wid + 1];
        float a0 = 0.f, a1 = 0.f, a2 = 0.f, a3 = 0.f;
        int e = beg + q;
        for (; e + 12 < end; e += 16) {          // 16 edges/wave-iter, 16 gathers in flight
            int c0 = col[e], c1 = col[e + 4], c2 = col[e + 8], c3 = col[e + 12];
            uint2 v0 = act ? hs2[(unsigned)c0 * PW2 + p] : make_uint2(0u, 0u);
            uint2 v1 = act ? hs2[(unsigned)c1 * PW2 + p] : make_uint2(0u, 0u);
            uint2 v2 = act ? hs2[(unsigned)c2 * PW2 + p] : make_uint2(0u, 0u);
            uint2 v3 = act ? hs2[(unsigned)c3 * PW2 + p] : make_uint2(0u, 0u);
            a0 += bfu_lo(v0.x) + bfu_lo(v1.x) + bfu_lo(v2.x) + bfu_lo(v3.x);
            a1 += bfu_hi(v0.x) + bfu_hi(v1.x) + bfu_hi(v2.x) + bfu_hi(v3.x);
            a2 += bfu_lo(v0.y) + bfu_lo(v1.y) + bfu_lo(v2.y) + bfu_lo(v3.y);
            a3 += bfu_hi(v0.y) + bfu_hi(v1.y) + bfu_hi(v2.y) + bfu_hi(v3.y);
        }
        if (e + 4 < end) {                       // >=2 edges left in this stream
            int c0 = col[e], c1 = col[e + 4];
            uint2 v0 = act ? hs2[(unsigned)c0 * PW2 + p] : make_uint2(0u, 0u);
            uint2 v1 = act ? hs2[(unsigned)c1 * PW2 + p] : make_uint2(0u, 0u);
            a0 += bfu_lo(v0.x) + bfu_lo(v1.x);
            a1 += bfu_hi(v0.x) + bfu_hi(v1.x);
            a2 += bfu_lo(v0.y) + bfu_lo(v1.y);
            a3 += bfu_hi(v0.y) + bfu_hi(v1.y);
            e += 8;
        }
        if (e < end) {                           // last remaining edge
            int c0 = col[e];
            uint2 v0 = act ? hs2[(unsigned)c0 * PW2 + p] : make_uint2(0u, 0u);
            a0 += bfu_lo(v0.x); a1 += bfu_hi(v0.x);
            a2 += bfu_lo(v0.y); a3 += bfu_hi(v0.y);
        }
        // combine the 4 stream partials
        a0 += __shfl_xor(a0, 16); a1 += __shfl_xor(a1, 16);
        a2 += __shfl_xor(a2, 16); a3 += __shfl_xor(a3, 16);
        a0 += __shfl_xor(a0, 32); a1 += __shfl_xor(a1, 32);
        a2 += __shfl_xor(a2, 32); a3 += __shfl_xor(a3, 32);

        const float di = dinv[wid];
        uint2 sv  = act ? hs2[(unsigned)wid * PW2 + p] : make_uint2(0u, 0u);
        float4 bv = act ? *(const float4*)&bias[4 * p] : make_float4(0.f, 0.f, 0.f, 0.f);
        float r0 = di * (a0 + bfu_lo(sv.x)) + bv.x;
        float r1 = di * (a1 + bfu_hi(sv.x)) + bv.y;
        float r2 = di * (a2 + bfu_lo(sv.y)) + bv.z;
        float r3 = di * (a3 + bfu_hi(sv.y)) + bv.w;
        if (RELU) {
            r0 = fmaxf(r0, 0.f); r1 = fmaxf(r1, 0.f);
            r2 = fmaxf(r2, 0.f); r3 = fmaxf(r3, 0.f);
        }
        if (LSM) {
            float m = act ? fmaxf(fmaxf(r0, r1), fmaxf(r2, r3)) : -INFINITY;
#pragma unroll
            for (int off = 8; off; off >>= 1) m = fmaxf(m, __shfl_xor(m, off));
            float ex = act ? (__expf(r0 - m) + __expf(r1 - m) + __expf(r2 - m) + __expf(r3 - m))
                           : 0.f;
#pragma unroll
            for (int off = 8; off; off >>= 1) ex += __shfl_xor(ex, off);
            float lse = m + __logf(ex);
            r0 -= lse; r1 -= lse; r2 -= lse; r3 -= lse;
        }
        if (q == 0 && act)
            *(float4*)&out[(size_t)wid * F + 4 * p] = make_float4(r0, r1, r2, r3);
    }
}

// ---------- GEMM2: h2s[N,40](bf16, pre-scaled) = dinv * (a[N,64] @ W2[64,40]) ----------
__launch_bounds__(256)
__global__ void k_gemm2(const float* __restrict__ a, const float* __restrict__ w,
                        const float* __restrict__ dinv, unsigned short* __restrict__ out, int n) {
    __shared__ float ws[HIDDEN * N_CLASS];
    for (int idx = threadIdx.x; idx < HIDDEN * N_CLASS; idx += 256) ws[idx] = w[idx];
    __syncthreads();
    int idx = blockIdx.x * 256 + threadIdx.x;
    if (idx >= n * N_CLASS) return;
    int i = idx / N_CLASS, j = idx - i * N_CLASS;
    float s = 0.f;
#pragma unroll
    for (int k = 0; k < HIDDEN; k += 4) {
        float4 xv = *(const float4*)&a[(size_t)i * HIDDEN + k];
        s = fmaf(xv.x, ws[k * N_CLASS + j], s);
        s = fmaf(xv.y, ws[(k + 1) * N_CLASS + j], s);
        s = fmaf(xv.z, ws[(k + 2) * N_CLASS + j], s);
        s = fmaf(xv.w, ws[(k + 3) * N_CLASS + j], s);
    }
    out[idx] = f2bf(dinv[i] * s);
}

extern "C" void kernel_launch(void* const* d_in, const int* in_sizes, int n_in,
                              void* d_out, int out_size, void* d_ws, size_t ws_size,
                              hipStream_t stream) {
    const float* x   = (const float*)d_in[0];
    const float* W1  = (const float*)d_in[1];
    const float* b1  = (const float*)d_in[2];
    const float* W2  = (const float*)d_in[3];
    const float* b2  = (const float*)d_in[4];
    const int*   ei  = (const int*)d_in[5];
    const int*   src = ei;
    const int*   dst = ei + N_EDGES;
    float*       out = (float*)d_out;

    char*  ws  = (char*)d_ws;
    size_t off = 0;
    auto alloc = [&](size_t bytes) -> void* {
        void* p = ws + off;
        off += (bytes + 255) & ~(size_t)255;
        return p;
    };
    int*            bcnt = (int*)alloc((size_t)NB * 4);
    int*            bptr = (int*)alloc((size_t)(NB + 1) * 4);
    int*            bcur = (int*)alloc((size_t)NB * 4);
    int*            rp   = (int*)alloc((size_t)(N_NODES + 1) * 4);
    int*            col  = (int*)alloc((size_t)N_EDGES * 4);
    float*          dinv = (float*)alloc((size_t)N_NODES * 4);
    unsigned short* w1t  = (unsigned short*)alloc((size_t)HIDDEN * KPAD * 2);
    unsigned short* h1s  = (unsigned short*)alloc((size_t)N_NODES * HIDDEN * 2);  // bf16, pre-scaled
    float*          h1a  = (float*)alloc((size_t)N_NODES * HIDDEN * 4);           // fp32
    int2*           ebuf = (int2*)h1a;            // alias: ebuf dead before agg1 writes h1a
    unsigned short* h2s  = h1s;                   // bf16, aliases h1s (dead after agg1)

    const int NBH = (N_EDGES + EPB - 1) / EPB;   // 98

    // CSR build (bucketed counting sort) + W1^T prep (also zeroes bcnt)
    k_prep_w1t<<<(HIDDEN * KPAD + 255) / 256, 256, 0, stream>>>(W1, w1t, bcnt);
    k_bhist<<<NBH, 1024, 0, stream>>>(dst, bcnt, N_EDGES);
    k_bscan<<<1, 1024, 0, stream>>>(bcnt, bptr, bcur);
    k_bfill<<<NBH, 1024, 0, stream>>>(src, dst, bcur, ebuf, N_EDGES);
    k_bucket_csr<<<NB, 256, 0, stream>>>(ebuf, bptr, rp, col, dinv, N_NODES);

    // layer 1
    k_gemm1<<<(N_NODES + 127) / 128, 512, 0, stream>>>(x, w1t, dinv, h1s, N_NODES);
    k_agg<HIDDEN, true, false><<<2048, 256, 0, stream>>>(
        (const uint2*)h1s, rp, col, dinv, b1, h1a, N_NODES);

    // layer 2 (+fused log_softmax)
    k_gemm2<<<(N_NODES * N_CLASS + 255) / 256, 256, 0, stream>>>(h1a, W2, dinv, h2s, N_NODES);
    k_agg<N_CLASS, false, true><<<2048, 256, 0, stream>>>(
        (const uint2*)h2s, rp, col, dinv, b2, out, N_NODES);
}